// Round 4
// baseline (225.750 us; speedup 1.0000x reference)
//
#include <hip/hip_runtime.h>

// ---------------------------------------------------------------------------
// MoE cross-attention decoder layer on MI355X (gfx950), bf16 MFMA pipeline.
// R13: gemm_qkv = R12's A-in-LDS(32KB) + W-direct-to-VGPR, with the two R12
// bugs fixed: (1) grid restored to (row,col,role) so A-tile sharers have the
// same blockid mod 8 -> same XCD L2 (R12's reorder tripled FETCH_SIZE);
// (2) W fragments double-buffered across K-steps (issued 2 steps ahead,
// single vmcnt(12) per step; vmcnt(0) only at the last). 3 blocks/CU via
// __launch_bounds__(256,3). cvt_all / attn / gemm_og / finalize unchanged.
// ---------------------------------------------------------------------------

typedef __bf16 bf16x8 __attribute__((ext_vector_type(8)));
typedef float f32x4 __attribute__((ext_vector_type(4)));
typedef unsigned int u32x4 __attribute__((ext_vector_type(4)));
typedef unsigned int u32x2 __attribute__((ext_vector_type(2)));
typedef unsigned short u16x4 __attribute__((ext_vector_type(4)));
typedef unsigned short us;

__device__ __forceinline__ us f2bf(float f) {
    unsigned u = __builtin_bit_cast(unsigned, f);
    u += 0x7FFFu + ((u >> 16) & 1u);
    return (us)(u >> 16);
}

__device__ __forceinline__ unsigned pack2(float lo, float hi) {
    return (unsigned)f2bf(lo) | ((unsigned)f2bf(hi) << 16);
}

__device__ __forceinline__ float bf2f(us v) {
    unsigned u = ((unsigned)v) << 16;
    return __builtin_bit_cast(float, u);
}

__device__ __forceinline__ bf16x8 ld_bf8(const us* p) {
    return __builtin_bit_cast(bf16x8, *reinterpret_cast<const u32x4*>(p));
}

__device__ __forceinline__ void gld_lds16(const us* g, us* l) {
    __builtin_amdgcn_global_load_lds(
        (const __attribute__((address_space(1))) unsigned int*)g,
        (__attribute__((address_space(3))) unsigned int*)l, 16, 0, 0);
}

// ---------------- fused converts + gate softmax ----------------------------
__launch_bounds__(256)
__global__ void cvt_all(const float* __restrict__ tgt, const float* __restrict__ qpos,
                        const float* __restrict__ mem, const float* __restrict__ pos,
                        const float* __restrict__ w_in, const float* __restrict__ w_out,
                        const float* __restrict__ w_gate, const float* __restrict__ b_gate,
                        us* __restrict__ Aq, us* __restrict__ Ak, us* __restrict__ Av,
                        us* __restrict__ Wb, us* __restrict__ WOb,
                        float* __restrict__ Gate)
{
    const int bid = blockIdx.x;
    const int tid = threadIdx.x;
    if (bid < 400) {
        const int i = bid * 256 + tid;
        const int lane = tid & 63;
        const int row = i >> 6;                 // = 4*bid + wave
        f32x4 a = reinterpret_cast<const f32x4*>(tgt)[i];
        f32x4 b = reinterpret_cast<const f32x4*>(qpos)[i];
        u16x4 r;
#pragma unroll
        for (int j = 0; j < 4; ++j) r[j] = f2bf(a[j] + b[j]);
        reinterpret_cast<u16x4*>(Aq)[i] = r;
        float g[5];
#pragma unroll
        for (int e = 0; e < 5; ++e) {
            f32x4 wg = *reinterpret_cast<const f32x4*>(w_gate + e * 256 + 4 * lane);
            float p = a[0] * wg[0] + a[1] * wg[1] + a[2] * wg[2] + a[3] * wg[3];
#pragma unroll
            for (int off = 32; off >= 1; off >>= 1) p += __shfl_xor(p, off, 64);
            g[e] = p + b_gate[e];
        }
        float mx = g[0];
#pragma unroll
        for (int e = 1; e < 5; ++e) mx = fmaxf(mx, g[e]);
        float sm = 0.0f;
#pragma unroll
        for (int e = 0; e < 5; ++e) { g[e] = __expf(g[e] - mx); sm += g[e]; }
        const float invs = 1.0f / sm;
        if (lane == 0) {
#pragma unroll
            for (int e = 0; e < 5; ++e) Gate[row * 5 + e] = g[e] * invs;
        }
    } else if (bid < 4496) {
        int i = (bid - 400) * 256 + tid;
        f32x4 m = reinterpret_cast<const f32x4*>(mem)[i];
        f32x4 p = reinterpret_cast<const f32x4*>(pos)[i];
        u16x4 rk, rv;
#pragma unroll
        for (int j = 0; j < 4; ++j) { rk[j] = f2bf(m[j] + p[j]); rv[j] = f2bf(m[j]); }
        reinterpret_cast<u16x4*>(Ak)[i] = rk;
        reinterpret_cast<u16x4*>(Av)[i] = rv;
    } else if (bid < 5456) {
        int i = (bid - 4496) * 256 + tid;
        f32x4 a = reinterpret_cast<const f32x4*>(w_in)[i];
        u16x4 r;
#pragma unroll
        for (int j = 0; j < 4; ++j) r[j] = f2bf(a[j]);
        reinterpret_cast<u16x4*>(Wb)[i] = r;
    } else {
        int i = (bid - 5456) * 256 + tid;
        f32x4 a = reinterpret_cast<const f32x4*>(w_out)[i];
        u16x4 r;
#pragma unroll
        for (int j = 0; j < 4; ++j) r[j] = f2bf(a[j]);
        reinterpret_cast<u16x4*>(WOb)[i] = r;
    }
}

// ---------------- QKV projection (R13) -------------------------------------
// grid (128, 2, 15): x = row block (XCD-aligned: sharers differ by 128|256 in
// block id == same id mod 8), y = col tile, z = role-expert.
// A staged to LDS (32 KB dbuf); W direct global->VGPR, double-buffered 2
// K-steps ahead. One vmcnt(12) per K-step; vmcnt(0) only at the last.
__launch_bounds__(256, 3)
__global__ void gemm_qkv(const us* __restrict__ Aq, const us* __restrict__ Ak,
                         const us* __restrict__ Av, const us* __restrict__ Wb,
                         const float* __restrict__ b_in,
                         us* __restrict__ Qb, us* __restrict__ Kb, us* __restrict__ Vb)
{
    const int rb   = blockIdx.x;       // row block
    const int col0 = blockIdx.y * 128;
    const int zr   = blockIdx.z;       // role-expert
    const us* A; const us* W; const float* bias; us* C;
    float scale; int M;
    if (zr < 5) {
        if (rb >= 13) return;
        A = Aq; W = Wb + (size_t)zr * 196608; bias = b_in + (size_t)zr * 768;
        C = Qb + (size_t)zr * 409600; scale = 0.17677669529663687f; M = 1600;
    } else if (zr < 10) {
        const int e = zr - 5;
        A = Ak; W = Wb + 65536 + (size_t)e * 196608; bias = b_in + (size_t)e * 768 + 256;
        C = Kb + (size_t)e * 4194304; scale = 1.0f; M = 16384;
    } else {
        const int e = zr - 10;
        A = Av; W = Wb + 131072 + (size_t)e * 196608; bias = b_in + (size_t)e * 768 + 512;
        C = Vb + (size_t)e * 4194304; scale = 1.0f; M = 16384;
    }
    const int row0 = rb * 128;

    __shared__ us As[2 * 8192];        // 32 KB: A-tile double buffer only
    const int tid  = threadIdx.x;
    const int lane = tid & 63;
    const int w    = tid >> 6;
    const int l15  = lane & 15;
    const int quad = lane >> 4;
    const int wm   = (w >> 1) * 64;
    const int wn   = (w & 1) * 64;
    const int srow = lane >> 3;
    const int gofs = ((lane & 7) ^ srow) * 8;

    // per-wave A stage: 4 gld_lds16 (one k-slice quarter, wave-uniform dest)
    auto stageA = [&](int buf, int kt) {
#pragma unroll
        for (int cc = 0; cc < 4; ++cc) {
            const int c = w * 4 + cc;
            gld_lds16(A + (size_t)(row0 + c * 8 + srow) * 256 + kt * 64 + gofs,
                      &As[buf * 8192 + c * 512]);
        }
    };
    // per-wave W fragment load: 8 global_load_dwordx4 into VGPRs
    auto loadW = [&](u32x4 (*dst)[4], int kt) {
#pragma unroll
        for (int kh = 0; kh < 2; ++kh)
#pragma unroll
            for (int ni = 0; ni < 4; ++ni)
                dst[kh][ni] = *reinterpret_cast<const u32x4*>(
                    W + (size_t)(col0 + wn + ni * 16 + l15) * 256 + kt * 64 + kh * 32 + quad * 8);
    };

    f32x4 acc[4][4] = {};
    u32x4 bf0[2][4], bf1[2][4];

    auto compute = [&](int cur, const u32x4 (*bq)[4]) {
#pragma unroll
        for (int kh = 0; kh < 2; ++kh) {
            bf16x8 af[4];
#pragma unroll
            for (int mi = 0; mi < 4; ++mi) {
                const int row = wm + mi * 16 + l15;
                const int seg = (kh * 4 + quad) ^ (row & 7);
                af[mi] = ld_bf8(&As[cur * 8192 + row * 64 + seg * 8]);
            }
#pragma unroll
            for (int mi = 0; mi < 4; ++mi)
#pragma unroll
                for (int ni = 0; ni < 4; ++ni)
                    acc[mi][ni] = __builtin_amdgcn_mfma_f32_16x16x32_bf16(
                        __builtin_bit_cast(bf16x8, bq[kh][ni]), af[mi], acc[mi][ni], 0, 0, 0);
        }
    };

    // prologue: queue = [A0(4), W0(8), A1(4), W1(8)] -- order pinned
    stageA(0, 0);  __builtin_amdgcn_sched_barrier(0);
    loadW(bf0, 0); __builtin_amdgcn_sched_barrier(0);
    stageA(1, 1);  __builtin_amdgcn_sched_barrier(0);
    loadW(bf1, 1); __builtin_amdgcn_sched_barrier(0);

    // kt = 0 : wait A0+W0 (leave A1,W1 = 12 in flight)
    asm volatile("s_waitcnt vmcnt(12)" ::: "memory");
    __builtin_amdgcn_s_barrier();
    __builtin_amdgcn_sched_barrier(0);
    compute(0, bf0);
    asm volatile("s_waitcnt lgkmcnt(0)" ::: "memory");
    __builtin_amdgcn_sched_barrier(0);
    __builtin_amdgcn_s_barrier();          // all waves done reading As[0]
    __builtin_amdgcn_sched_barrier(0);
    stageA(0, 2);  __builtin_amdgcn_sched_barrier(0);
    loadW(bf0, 2); __builtin_amdgcn_sched_barrier(0);

    // kt = 1 : queue [A1,W1,A2,W2] -> wait to 12
    asm volatile("s_waitcnt vmcnt(12)" ::: "memory");
    __builtin_amdgcn_s_barrier();
    __builtin_amdgcn_sched_barrier(0);
    compute(1, bf1);
    asm volatile("s_waitcnt lgkmcnt(0)" ::: "memory");
    __builtin_amdgcn_sched_barrier(0);
    __builtin_amdgcn_s_barrier();          // all waves done reading As[1]
    __builtin_amdgcn_sched_barrier(0);
    stageA(1, 3);  __builtin_amdgcn_sched_barrier(0);
    loadW(bf1, 3); __builtin_amdgcn_sched_barrier(0);

    // kt = 2 : queue [A2,W2,A3,W3] -> wait to 12 (no tail: As[0] not reused)
    asm volatile("s_waitcnt vmcnt(12)" ::: "memory");
    __builtin_amdgcn_s_barrier();
    __builtin_amdgcn_sched_barrier(0);
    compute(0, bf0);

    // kt = 3 : drain
    asm volatile("s_waitcnt vmcnt(0)" ::: "memory");
    __builtin_amdgcn_s_barrier();
    __builtin_amdgcn_sched_barrier(0);
    compute(1, bf1);

    // ---- epilogue: bias + scale + pack bf16 + store ----
#pragma unroll
    for (int mi = 0; mi < 4; ++mi) {
        const int row = row0 + wm + mi * 16 + l15;
        if (row < M) {
#pragma unroll
            for (int ni = 0; ni < 4; ++ni) {
                const int colb = col0 + wn + ni * 16 + quad * 4;
                const f32x4 b4 = *reinterpret_cast<const f32x4*>(bias + colb);
                u32x2 pk;
                pk[0] = pack2((acc[mi][ni][0] + b4[0]) * scale,
                              (acc[mi][ni][1] + b4[1]) * scale);
                pk[1] = pack2((acc[mi][ni][2] + b4[2]) * scale,
                              (acc[mi][ni][3] + b4[3]) * scale);
                *reinterpret_cast<u32x2*>(C + (size_t)row * 256 + colb) = pk;
            }
        }
    }
}

// ---------------- out-proj GEMM with fused split-combine -------------------
__launch_bounds__(256)
__global__ void gemm_og(const us* __restrict__ PO, const float* __restrict__ PL,
                        const us* __restrict__ WOb, const float* __restrict__ b_out,
                        float* __restrict__ OUTf)
{
    const int e = blockIdx.z;
    const us* W = WOb + (size_t)e * 65536;
    const float* bias = b_out + (size_t)e * 256;
    float* Cout = OUTf + (size_t)e * 409600;

    const int row0 = blockIdx.x * 128;
    const int col0 = blockIdx.y * 128;
    __shared__ us As[2 * 8192];
    __shared__ us Bs[2 * 8192];
    const int tid  = threadIdx.x;
    const int lane = tid & 63;
    const int w    = tid >> 6;
    const int l15  = lane & 15;
    const int quad = lane >> 4;
    const int wm   = (w >> 1) * 64;
    const int wn   = (w & 1) * 64;
    const int srow = lane >> 3;
    const int gofs = ((lane & 7) ^ srow) * 8;

    u32x4 POr[4][4];   // [chunk][split]
    float Lr[4];

    auto loadA = [&](int kt) {
#pragma unroll
        for (int cc = 0; cc < 4; ++cc) {
            const int c = w * 4 + cc;
            int grow = row0 + c * 8 + srow;
            if (grow > 1599) grow = 1599;
            const int d0 = kt * 64 + gofs;
            const size_t base = (size_t)e * 409600 + (size_t)grow * 256 + d0;
#pragma unroll
            for (int s = 0; s < 4; ++s)
                POr[cc][s] = *reinterpret_cast<const u32x4*>(PO + base + (size_t)s * 2048000);
            const int l = grow >> 4, bb = grow & 15, h = d0 >> 5;
            float L = 0.0f;
#pragma unroll
            for (int s = 0; s < 4; ++s)
                L += PL[((((size_t)s * 5 + e) * 16 + bb) * 8 + h) * 128 + l];
            Lr[cc] = L;
        }
    };
    auto writeA = [&](int buf) {
#pragma unroll
        for (int cc = 0; cc < 4; ++cc) {
            const float inv = 1.0f / Lr[cc];
            u32x4 pk;
#pragma unroll
            for (int j = 0; j < 4; ++j) {
                float v0 = 0.0f, v1 = 0.0f;
#pragma unroll
                for (int s = 0; s < 4; ++s) {
                    const unsigned u = POr[cc][s][j];
                    v0 += __builtin_bit_cast(float, u << 16);
                    v1 += __builtin_bit_cast(float, u & 0xffff0000u);
                }
                pk[j] = pack2(v0 * inv, v1 * inv);
            }
            *reinterpret_cast<u32x4*>(&As[buf * 8192 + (w * 4 + cc) * 512 + lane * 8]) = pk;
        }
    };
    auto loadW = [&](int buf, int kt) {
#pragma unroll
        for (int cc = 0; cc < 4; ++cc) {
            const int c = w * 4 + cc;
            const int row = c * 8 + srow;
            gld_lds16(W + (size_t)(col0 + row) * 256 + kt * 64 + gofs,
                      &Bs[buf * 8192 + c * 512]);
        }
    };

    loadA(0);
    loadW(0, 0);
    writeA(0);
    __syncthreads();

    f32x4 acc[4][4] = {};

#pragma unroll
    for (int kt = 0; kt < 4; ++kt) {
        const int cur = kt & 1;
        if (kt < 3) {
            loadA(kt + 1);
            loadW(cur ^ 1, kt + 1);
        }
#pragma unroll
        for (int kh = 0; kh < 2; ++kh) {
            bf16x8 af[4], bf[4];
#pragma unroll
            for (int mi = 0; mi < 4; ++mi) {
                const int row = wm + mi * 16 + l15;
                const int seg = (kh * 4 + quad) ^ (row & 7);
                af[mi] = ld_bf8(&As[cur * 8192 + row * 64 + seg * 8]);
            }
#pragma unroll
            for (int ni = 0; ni < 4; ++ni) {
                const int col = wn + ni * 16 + l15;
                const int seg = (kh * 4 + quad) ^ (col & 7);
                bf[ni] = ld_bf8(&Bs[cur * 8192 + col * 64 + seg * 8]);
            }
#pragma unroll
            for (int mi = 0; mi < 4; ++mi)
#pragma unroll
                for (int ni = 0; ni < 4; ++ni)
                    acc[mi][ni] = __builtin_amdgcn_mfma_f32_16x16x32_bf16(bf[ni], af[mi], acc[mi][ni], 0, 0, 0);
        }
        if (kt < 3) {
            writeA(cur ^ 1);
            __syncthreads();
        }
    }

#pragma unroll
    for (int mi = 0; mi < 4; ++mi) {
        const int row = row0 + wm + mi * 16 + l15;
        if (row < 1600) {
#pragma unroll
            for (int ni = 0; ni < 4; ++ni) {
                const int colb = col0 + wn + ni * 16 + quad * 4;
                const f32x4 b4 = *reinterpret_cast<const f32x4*>(bias + colb);
                f32x4 v;
#pragma unroll
                for (int r = 0; r < 4; ++r) v[r] = acc[mi][ni][r] + b4[r];
                *reinterpret_cast<f32x4*>(Cout + (size_t)row * 256 + colb) = v;
            }
        }
    }
}

// ---------------- split-K attention (unchanged) ----------------------------
__device__ __forceinline__ int vrow(int d) { return d * 264 + 8 * (d >> 3); }

__launch_bounds__(512)
__global__ void attn(const us* __restrict__ Qb, const us* __restrict__ Kb,
                     const us* __restrict__ Vb, us* __restrict__ PO,
                     float* __restrict__ PL)
{
    const int h = blockIdx.x;
    const int z = blockIdx.y;
    const int s = blockIdx.z;
    const int e = z >> 4, b = z & 15;
    const int tid  = threadIdx.x;
    const int w    = tid >> 6;
    const int lane = tid & 63;
    const int l15  = lane & 15, quad = lane >> 4;
    __shared__ us Ks[256 * 32];
    __shared__ us Vs[8464];
    __shared__ us Ps[7][16 * 40];

    const int key0 = s * 256;
    {
        const int kl  = lane >> 2;
        const int seg = lane & 3;
        const us* kg = Kb + ((size_t)((e * 1024 + key0 + w * 16 + kl) * 16 + b)) * 256
                          + h * 32 + seg * 8;
        gld_lds16(kg, &Ks[w * 512]);
        gld_lds16(kg + (size_t)128 * 16 * 256, &Ks[4096 + w * 512]);

        const int kv = tid >> 2;
        const int sg = tid & 3;
        const us* vg = Vb + ((size_t)((e * 1024 + key0 + kv) * 16 + b)) * 256
                          + h * 32 + sg * 8;
        u32x4 v0 = *reinterpret_cast<const u32x4*>(vg);
        u32x4 v1 = *reinterpret_cast<const u32x4*>(vg + (size_t)128 * 16 * 256);
#pragma unroll
        for (int j = 0; j < 4; ++j) {
            const int d0 = sg * 8 + 2 * j;
            const int e0 = vrow(d0);
            const int e1 = e0 + 264;
            Vs[e0 + kv]       = (us)(v0[j] & 0xffff);
            Vs[e1 + kv]       = (us)(v0[j] >> 16);
            Vs[e0 + 128 + kv] = (us)(v1[j] & 0xffff);
            Vs[e1 + 128 + kv] = (us)(v1[j] >> 16);
        }
    }
    u32x4 qraw = {0u, 0u, 0u, 0u};
    if (w < 7) {
        const int l = w * 16 + l15;
        if (l < 100)
            qraw = *reinterpret_cast<const u32x4*>(
                Qb + ((size_t)((e * 100 + l) * 16 + b)) * 256 + h * 32 + quad * 8);
    }
    const bf16x8 qf = __builtin_bit_cast(bf16x8, qraw);

    __syncthreads();

    if (w >= 7) return;

    const f32x4 zacc = {};
    f32x4 o0 = {}, o1 = {};
    float lsum = 0.0f;

    for (int c = 0; c < 8; ++c) {
        bf16x8 kf0 = ld_bf8(&Ks[(c * 32 + l15) * 32 + quad * 8]);
        bf16x8 kf1 = ld_bf8(&Ks[(c * 32 + 16 + l15) * 32 + quad * 8]);
        f32x4 s0 = __builtin_amdgcn_mfma_f32_16x16x32_bf16(kf0, qf, zacc, 0, 0, 0);
        f32x4 s1 = __builtin_amdgcn_mfma_f32_16x16x32_bf16(kf1, qf, zacc, 0, 0, 0);
        float p0[4], p1[4];
#pragma unroll
        for (int r = 0; r < 4; ++r) {
            p0[r] = __expf(s0[r]);
            p1[r] = __expf(s1[r]);
            lsum += p0[r] + p1[r];
        }
        u32x2 w0, w1;
        w0[0] = pack2(p0[0], p0[1]);
        w0[1] = pack2(p0[2], p0[3]);
        w1[0] = pack2(p1[0], p1[1]);
        w1[1] = pack2(p1[2], p1[3]);
        *reinterpret_cast<u32x2*>(&Ps[w][l15 * 40 + quad * 4])      = w0;
        *reinterpret_cast<u32x2*>(&Ps[w][l15 * 40 + 16 + quad * 4]) = w1;
        bf16x8 pf  = ld_bf8(&Ps[w][l15 * 40 + quad * 8]);
        bf16x8 vf0 = ld_bf8(&Vs[vrow(l15) + c * 32 + quad * 8]);
        bf16x8 vf1 = ld_bf8(&Vs[vrow(16 + l15) + c * 32 + quad * 8]);
        o0 = __builtin_amdgcn_mfma_f32_16x16x32_bf16(pf, vf0, o0, 0, 0, 0);
        o1 = __builtin_amdgcn_mfma_f32_16x16x32_bf16(pf, vf1, o1, 0, 0, 0);
    }

    lsum += __shfl_xor(lsum, 16, 64);
    lsum += __shfl_xor(lsum, 32, 64);

#pragma unroll
    for (int r = 0; r < 4; ++r) {
        const int row = w * 16 + quad * 4 + r;
        if (row < 100) {
            const size_t o = (((size_t)((s * 5 + e) * 100 + row)) * 16 + b) * 256 + h * 32;
            PO[o + l15]      = f2bf(o0[r]);
            PO[o + 16 + l15] = f2bf(o1[r]);
        }
    }
    const int q = w * 16 + l15;
    if (quad == 0 && q < 100)
        PL[((((size_t)s * 5 + e) * 16 + b) * 8 + h) * 128 + q] = lsum;
}

// ---------------- gate-weighted mix + residual + LayerNorm -----------------
__launch_bounds__(256)
__global__ void finalize(const float* __restrict__ tgt, const float* __restrict__ Gate,
                         const float* __restrict__ OUTf,
                         const float* __restrict__ gamma, const float* __restrict__ beta,
                         float* __restrict__ out)
{
    const int row = blockIdx.x;
    const int d = threadIdx.x;
    __shared__ float red[8];
    const float t = tgt[(size_t)row * 256 + d];

    float mo = 0.0f;
#pragma unroll
    for (int e = 0; e < 5; ++e)
        mo += Gate[row * 5 + e] * OUTf[((size_t)e * 1600 + row) * 256 + d];
    const float x = t + mo;

    float p1 = x, p2 = x * x;
#pragma unroll
    for (int off = 32; off >= 1; off >>= 1) {
        p1 += __shfl_xor(p1, off, 64);
        p2 += __shfl_xor(p2, off, 64);
    }
    if ((d & 63) == 0) { red[d >> 6] = p1; red[4 + (d >> 6)] = p2; }
    __syncthreads();
    const float mean = (red[0] + red[1] + red[2] + red[3]) * (1.0f / 256.0f);
    const float msq  = (red[4] + red[5] + red[6] + red[7]) * (1.0f / 256.0f);
    const float var  = msq - mean * mean;

    out[(size_t)row * 256 + d] = (x - mean) * rsqrtf(var + 1e-5f) * gamma[d] + beta[d];
}

// ---------------------------------------------------------------------------
extern "C" void kernel_launch(void* const* d_in, const int* in_sizes, int n_in,
                              void* d_out, int out_size, void* d_ws, size_t ws_size,
                              hipStream_t stream)
{
    const float* tgt    = (const float*)d_in[0];
    const float* mem    = (const float*)d_in[1];
    const float* qpos   = (const float*)d_in[2];
    const float* pos    = (const float*)d_in[3];
    const float* w_in   = (const float*)d_in[4];
    const float* b_in   = (const float*)d_in[5];
    const float* w_out  = (const float*)d_in[6];
    const float* b_out  = (const float*)d_in[7];
    const float* w_gate = (const float*)d_in[8];
    const float* b_gate = (const float*)d_in[9];
    const float* ln_g   = (const float*)d_in[10];
    const float* ln_b   = (const float*)d_in[11];
    float* out = (float*)d_out;

    char* p = (char*)d_ws;
    auto alloc = [&](size_t n) { char* r = p; p += (n + 255) & ~(size_t)255; return r; };

    us* Aq   = (us*)alloc(409600ull * 2);       // dead after gemm_qkv
    us* Ak   = (us*)alloc(4194304ull * 2);      // dead after gemm_qkv
    us* Av   = (us*)alloc(4194304ull * 2);      // dead after gemm_qkv
    us* Wb   = (us*)alloc(983040ull * 2);
    us* WOb  = (us*)alloc(327680ull * 2);
    us* Qb   = (us*)alloc(5ull * 409600 * 2);
    us* Kb   = (us*)alloc(5ull * 4194304 * 2);
    us* Vb   = (us*)alloc(5ull * 4194304 * 2);
    float* OUTf  = (float*)alloc(5ull * 409600 * 4);
    float* Gate  = (float*)alloc(1600ull * 5 * 4);
    // Attention partials alias the dead cvt region (Aq..Av): 16.4+0.33 < 17.7 MB
    us*    PO = (us*)d_ws;                          // [4][5][100][16][256] bf16
    float* PL = (float*)((char*)d_ws + 16384000);   // [4*5*16*8][128] f32

    cvt_all<<<5776, 256, 0, stream>>>(tgt, qpos, mem, pos, w_in, w_out,
                                      w_gate, b_gate, Aq, Ak, Av, Wb, WOb, Gate);

    gemm_qkv<<<dim3(128, 2, 15), 256, 0, stream>>>(Aq, Ak, Av, Wb, b_in, Qb, Kb, Vb);

    attn<<<dim3(8, 80, 4), 512, 0, stream>>>(Qb, Kb, Vb, PO, PL);

    gemm_og<<<dim3(13, 2, 5), 256, 0, stream>>>(PO, PL, WOb, b_out, OUTf);

    finalize<<<1600, 256, 0, stream>>>(tgt, Gate, OUTf, ln_g, ln_b, out);
}

// Round 5
// 205.210 us; speedup vs baseline: 1.1001x; 1.1001x over previous
//
#include <hip/hip_runtime.h>

// ---------------------------------------------------------------------------
// MoE cross-attention decoder layer on MI355X (gfx950), bf16 MFMA pipeline.
// R14: gemm_qkv: A staged to LDS (32 KB dbuf, gld_lds); W read direct
// global->VGPR from a FRAGMENT-MAJOR Wb layout ([g=k/8][col][8] per
// expert-role, emitted by cvt_all) so each W-fragment load is 4x256B
// contiguous (R13's scattered-load failure fixed). No W dbuf (R13's compiler
// trap); latency hidden by 4-5 blocks/CU (32KB LDS, ~80 VGPR). vmcnt(4)
// per kt keeps next A-tile in flight; stores only in epilogue. Grid
// (128,2,15) XCD-aligned (FETCH ~20MB verified). attn/gemm_og/finalize
// unchanged.
// ---------------------------------------------------------------------------

typedef __bf16 bf16x8 __attribute__((ext_vector_type(8)));
typedef float f32x4 __attribute__((ext_vector_type(4)));
typedef unsigned int u32x4 __attribute__((ext_vector_type(4)));
typedef unsigned int u32x2 __attribute__((ext_vector_type(2)));
typedef unsigned short u16x4 __attribute__((ext_vector_type(4)));
typedef unsigned short us;

__device__ __forceinline__ us f2bf(float f) {
    unsigned u = __builtin_bit_cast(unsigned, f);
    u += 0x7FFFu + ((u >> 16) & 1u);
    return (us)(u >> 16);
}

__device__ __forceinline__ unsigned pack2(float lo, float hi) {
    return (unsigned)f2bf(lo) | ((unsigned)f2bf(hi) << 16);
}

__device__ __forceinline__ float bf2f(us v) {
    unsigned u = ((unsigned)v) << 16;
    return __builtin_bit_cast(float, u);
}

__device__ __forceinline__ bf16x8 ld_bf8(const us* p) {
    return __builtin_bit_cast(bf16x8, *reinterpret_cast<const u32x4*>(p));
}

__device__ __forceinline__ void gld_lds16(const us* g, us* l) {
    __builtin_amdgcn_global_load_lds(
        (const __attribute__((address_space(1))) unsigned int*)g,
        (__attribute__((address_space(3))) unsigned int*)l, 16, 0, 0);
}

// ---------------- fused converts + gate softmax ----------------------------
// Wb is written FRAGMENT-MAJOR: per (e,role) 65536-elem block laid out as
// [g 0..31][col 0..255][8], g = k/8. Same (e,role) base offsets as before.
__launch_bounds__(256)
__global__ void cvt_all(const float* __restrict__ tgt, const float* __restrict__ qpos,
                        const float* __restrict__ mem, const float* __restrict__ pos,
                        const float* __restrict__ w_in, const float* __restrict__ w_out,
                        const float* __restrict__ w_gate, const float* __restrict__ b_gate,
                        us* __restrict__ Aq, us* __restrict__ Ak, us* __restrict__ Av,
                        us* __restrict__ Wb, us* __restrict__ WOb,
                        float* __restrict__ Gate)
{
    const int bid = blockIdx.x;
    const int tid = threadIdx.x;
    if (bid < 400) {
        const int i = bid * 256 + tid;
        const int lane = tid & 63;
        const int row = i >> 6;                 // = 4*bid + wave
        f32x4 a = reinterpret_cast<const f32x4*>(tgt)[i];
        f32x4 b = reinterpret_cast<const f32x4*>(qpos)[i];
        u16x4 r;
#pragma unroll
        for (int j = 0; j < 4; ++j) r[j] = f2bf(a[j] + b[j]);
        reinterpret_cast<u16x4*>(Aq)[i] = r;
        float g[5];
#pragma unroll
        for (int e = 0; e < 5; ++e) {
            f32x4 wg = *reinterpret_cast<const f32x4*>(w_gate + e * 256 + 4 * lane);
            float p = a[0] * wg[0] + a[1] * wg[1] + a[2] * wg[2] + a[3] * wg[3];
#pragma unroll
            for (int off = 32; off >= 1; off >>= 1) p += __shfl_xor(p, off, 64);
            g[e] = p + b_gate[e];
        }
        float mx = g[0];
#pragma unroll
        for (int e = 1; e < 5; ++e) mx = fmaxf(mx, g[e]);
        float sm = 0.0f;
#pragma unroll
        for (int e = 0; e < 5; ++e) { g[e] = __expf(g[e] - mx); sm += g[e]; }
        const float invs = 1.0f / sm;
        if (lane == 0) {
#pragma unroll
            for (int e = 0; e < 5; ++e) Gate[row * 5 + e] = g[e] * invs;
        }
    } else if (bid < 4496) {
        int i = (bid - 400) * 256 + tid;
        f32x4 m = reinterpret_cast<const f32x4*>(mem)[i];
        f32x4 p = reinterpret_cast<const f32x4*>(pos)[i];
        u16x4 rk, rv;
#pragma unroll
        for (int j = 0; j < 4; ++j) { rk[j] = f2bf(m[j] + p[j]); rv[j] = f2bf(m[j]); }
        reinterpret_cast<u16x4*>(Ak)[i] = rk;
        reinterpret_cast<u16x4*>(Av)[i] = rv;
    } else if (bid < 5456) {
        int i = (bid - 4496) * 256 + tid;       // f32x4 index into w_in
        f32x4 a = reinterpret_cast<const f32x4*>(w_in)[i];
        u16x4 r;
#pragma unroll
        for (int j = 0; j < 4; ++j) r[j] = f2bf(a[j]);
        // decompose: w_in[e][row 768][k 256], i covers k-quad kq4 = 4 floats
        const int e    = i / 49152;             // 768*64
        const int rem  = i % 49152;
        const int row  = rem >> 6;              // 0..767
        const int kq4  = rem & 63;              // which f32x4 in the row
        const int role = row >> 8;              // 0=q 1=k 2=v
        const int col  = row & 255;
        const int g    = kq4 >> 1;              // k granule (8 elems)
        const int sub  = kq4 & 1;               // which half of the granule
        const size_t dst = (size_t)(e * 3 + role) * 65536
                         + ((size_t)(g * 256 + col)) * 8 + sub * 4;
        *reinterpret_cast<u16x4*>(Wb + dst) = r;
    } else {
        int i = (bid - 5456) * 256 + tid;
        f32x4 a = reinterpret_cast<const f32x4*>(w_out)[i];
        u16x4 r;
#pragma unroll
        for (int j = 0; j < 4; ++j) r[j] = f2bf(a[j]);
        reinterpret_cast<u16x4*>(WOb)[i] = r;
    }
}

// ---------------- QKV projection (R14) -------------------------------------
// grid (128, 2, 15): x = row block (XCD-aligned), y = col tile, z = role-exp.
// A in LDS (32 KB dbuf via gld_lds); W direct from fragment-major Wb
// (contiguous 256B per 16-lane group). One vmcnt(4) per kt; vmcnt(0) at last.
__launch_bounds__(256, 4)
__global__ void gemm_qkv(const us* __restrict__ Aq, const us* __restrict__ Ak,
                         const us* __restrict__ Av, const us* __restrict__ Wb,
                         const float* __restrict__ b_in,
                         us* __restrict__ Qb, us* __restrict__ Kb, us* __restrict__ Vb)
{
    const int rb   = blockIdx.x;       // row block
    const int col0 = blockIdx.y * 128;
    const int zr   = blockIdx.z;       // role-expert
    const us* A; const us* W; const float* bias; us* C;
    float scale; int M;
    if (zr < 5) {
        if (rb >= 13) return;
        A = Aq; W = Wb + (size_t)zr * 196608; bias = b_in + (size_t)zr * 768;
        C = Qb + (size_t)zr * 409600; scale = 0.17677669529663687f; M = 1600;
    } else if (zr < 10) {
        const int e = zr - 5;
        A = Ak; W = Wb + 65536 + (size_t)e * 196608; bias = b_in + (size_t)e * 768 + 256;
        C = Kb + (size_t)e * 4194304; scale = 1.0f; M = 16384;
    } else {
        const int e = zr - 10;
        A = Av; W = Wb + 131072 + (size_t)e * 196608; bias = b_in + (size_t)e * 768 + 512;
        C = Vb + (size_t)e * 4194304; scale = 1.0f; M = 16384;
    }
    const int row0 = rb * 128;

    __shared__ us As[2 * 8192];        // 32 KB: A-tile double buffer only
    const int tid  = threadIdx.x;
    const int lane = tid & 63;
    const int w    = tid >> 6;
    const int l15  = lane & 15;
    const int quad = lane >> 4;
    const int wm   = (w >> 1) * 64;
    const int wn   = (w & 1) * 64;
    const int srow = lane >> 3;
    const int gofs = ((lane & 7) ^ srow) * 8;

    auto stageA = [&](int buf, int kt) {
#pragma unroll
        for (int cc = 0; cc < 4; ++cc) {
            const int c = w * 4 + cc;
            gld_lds16(A + (size_t)(row0 + c * 8 + srow) * 256 + kt * 64 + gofs,
                      &As[buf * 8192 + c * 512]);
        }
    };

    f32x4 acc[4][4] = {};

    stageA(0, 0);
    __builtin_amdgcn_sched_barrier(0);

#pragma unroll
    for (int kt = 0; kt < 4; ++kt) {
        const int cur = kt & 1;
        // W fragments for this k-tile, fragment-major: granule g = kt*8+kh*4+quad,
        // 16 lanes x 16B = 256B contiguous per (kh,ni).
        u32x4 bf[2][4];
#pragma unroll
        for (int kh = 0; kh < 2; ++kh)
#pragma unroll
            for (int ni = 0; ni < 4; ++ni)
                bf[kh][ni] = *reinterpret_cast<const u32x4*>(
                    W + (((size_t)(kt * 8 + kh * 4 + quad) * 256
                          + (col0 + wn + ni * 16 + l15)) * 8));
        __builtin_amdgcn_sched_barrier(0);
        if (kt < 3) stageA(cur ^ 1, kt + 1);
        __builtin_amdgcn_sched_barrier(0);
        // retire A(kt) [oldest] + W(kt); leave A(kt+1)'s 4 in flight
        if (kt < 3) asm volatile("s_waitcnt vmcnt(4)" ::: "memory");
        else        asm volatile("s_waitcnt vmcnt(0)" ::: "memory");
        __builtin_amdgcn_s_barrier();          // all waves' stage(kt) landed
        __builtin_amdgcn_sched_barrier(0);
#pragma unroll
        for (int kh = 0; kh < 2; ++kh) {
            bf16x8 af[4];
#pragma unroll
            for (int mi = 0; mi < 4; ++mi) {
                const int row = wm + mi * 16 + l15;
                const int seg = (kh * 4 + quad) ^ (row & 7);
                af[mi] = ld_bf8(&As[cur * 8192 + row * 64 + seg * 8]);
            }
#pragma unroll
            for (int mi = 0; mi < 4; ++mi)
#pragma unroll
                for (int ni = 0; ni < 4; ++ni)
                    acc[mi][ni] = __builtin_amdgcn_mfma_f32_16x16x32_bf16(
                        __builtin_bit_cast(bf16x8, bf[kh][ni]), af[mi], acc[mi][ni], 0, 0, 0);
        }
        if (kt < 3) {
            asm volatile("s_waitcnt lgkmcnt(0)" ::: "memory");
            __builtin_amdgcn_sched_barrier(0);
            __builtin_amdgcn_s_barrier();      // all waves done reading As[cur]
            __builtin_amdgcn_sched_barrier(0);
        }
    }

    // ---- epilogue: bias + scale + pack bf16 + store (stores only here) ----
#pragma unroll
    for (int mi = 0; mi < 4; ++mi) {
        const int row = row0 + wm + mi * 16 + l15;
        if (row < M) {
#pragma unroll
            for (int ni = 0; ni < 4; ++ni) {
                const int colb = col0 + wn + ni * 16 + quad * 4;
                const f32x4 b4 = *reinterpret_cast<const f32x4*>(bias + colb);
                u32x2 pk;
                pk[0] = pack2((acc[mi][ni][0] + b4[0]) * scale,
                              (acc[mi][ni][1] + b4[1]) * scale);
                pk[1] = pack2((acc[mi][ni][2] + b4[2]) * scale,
                              (acc[mi][ni][3] + b4[3]) * scale);
                *reinterpret_cast<u32x2*>(C + (size_t)row * 256 + colb) = pk;
            }
        }
    }
}

// ---------------- out-proj GEMM with fused split-combine -------------------
__launch_bounds__(256)
__global__ void gemm_og(const us* __restrict__ PO, const float* __restrict__ PL,
                        const us* __restrict__ WOb, const float* __restrict__ b_out,
                        float* __restrict__ OUTf)
{
    const int e = blockIdx.z;
    const us* W = WOb + (size_t)e * 65536;
    const float* bias = b_out + (size_t)e * 256;
    float* Cout = OUTf + (size_t)e * 409600;

    const int row0 = blockIdx.x * 128;
    const int col0 = blockIdx.y * 128;
    __shared__ us As[2 * 8192];
    __shared__ us Bs[2 * 8192];
    const int tid  = threadIdx.x;
    const int lane = tid & 63;
    const int w    = tid >> 6;
    const int l15  = lane & 15;
    const int quad = lane >> 4;
    const int wm   = (w >> 1) * 64;
    const int wn   = (w & 1) * 64;
    const int srow = lane >> 3;
    const int gofs = ((lane & 7) ^ srow) * 8;

    u32x4 POr[4][4];   // [chunk][split]
    float Lr[4];

    auto loadA = [&](int kt) {
#pragma unroll
        for (int cc = 0; cc < 4; ++cc) {
            const int c = w * 4 + cc;
            int grow = row0 + c * 8 + srow;
            if (grow > 1599) grow = 1599;
            const int d0 = kt * 64 + gofs;
            const size_t base = (size_t)e * 409600 + (size_t)grow * 256 + d0;
#pragma unroll
            for (int s = 0; s < 4; ++s)
                POr[cc][s] = *reinterpret_cast<const u32x4*>(PO + base + (size_t)s * 2048000);
            const int l = grow >> 4, bb = grow & 15, h = d0 >> 5;
            float L = 0.0f;
#pragma unroll
            for (int s = 0; s < 4; ++s)
                L += PL[((((size_t)s * 5 + e) * 16 + bb) * 8 + h) * 128 + l];
            Lr[cc] = L;
        }
    };
    auto writeA = [&](int buf) {
#pragma unroll
        for (int cc = 0; cc < 4; ++cc) {
            const float inv = 1.0f / Lr[cc];
            u32x4 pk;
#pragma unroll
            for (int j = 0; j < 4; ++j) {
                float v0 = 0.0f, v1 = 0.0f;
#pragma unroll
                for (int s = 0; s < 4; ++s) {
                    const unsigned u = POr[cc][s][j];
                    v0 += __builtin_bit_cast(float, u << 16);
                    v1 += __builtin_bit_cast(float, u & 0xffff0000u);
                }
                pk[j] = pack2(v0 * inv, v1 * inv);
            }
            *reinterpret_cast<u32x4*>(&As[buf * 8192 + (w * 4 + cc) * 512 + lane * 8]) = pk;
        }
    };
    auto loadW = [&](int buf, int kt) {
#pragma unroll
        for (int cc = 0; cc < 4; ++cc) {
            const int c = w * 4 + cc;
            const int row = c * 8 + srow;
            gld_lds16(W + (size_t)(col0 + row) * 256 + kt * 64 + gofs,
                      &Bs[buf * 8192 + c * 512]);
        }
    };

    loadA(0);
    loadW(0, 0);
    writeA(0);
    __syncthreads();

    f32x4 acc[4][4] = {};

#pragma unroll
    for (int kt = 0; kt < 4; ++kt) {
        const int cur = kt & 1;
        if (kt < 3) {
            loadA(kt + 1);
            loadW(cur ^ 1, kt + 1);
        }
#pragma unroll
        for (int kh = 0; kh < 2; ++kh) {
            bf16x8 af[4], bf[4];
#pragma unroll
            for (int mi = 0; mi < 4; ++mi) {
                const int row = wm + mi * 16 + l15;
                const int seg = (kh * 4 + quad) ^ (row & 7);
                af[mi] = ld_bf8(&As[cur * 8192 + row * 64 + seg * 8]);
            }
#pragma unroll
            for (int ni = 0; ni < 4; ++ni) {
                const int col = wn + ni * 16 + l15;
                const int seg = (kh * 4 + quad) ^ (col & 7);
                bf[ni] = ld_bf8(&Bs[cur * 8192 + col * 64 + seg * 8]);
            }
#pragma unroll
            for (int mi = 0; mi < 4; ++mi)
#pragma unroll
                for (int ni = 0; ni < 4; ++ni)
                    acc[mi][ni] = __builtin_amdgcn_mfma_f32_16x16x32_bf16(bf[ni], af[mi], acc[mi][ni], 0, 0, 0);
        }
        if (kt < 3) {
            writeA(cur ^ 1);
            __syncthreads();
        }
    }

#pragma unroll
    for (int mi = 0; mi < 4; ++mi) {
        const int row = row0 + wm + mi * 16 + l15;
        if (row < 1600) {
#pragma unroll
            for (int ni = 0; ni < 4; ++ni) {
                const int colb = col0 + wn + ni * 16 + quad * 4;
                const f32x4 b4 = *reinterpret_cast<const f32x4*>(bias + colb);
                f32x4 v;
#pragma unroll
                for (int r = 0; r < 4; ++r) v[r] = acc[mi][ni][r] + b4[r];
                *reinterpret_cast<f32x4*>(Cout + (size_t)row * 256 + colb) = v;
            }
        }
    }
}

// ---------------- split-K attention (unchanged) ----------------------------
__device__ __forceinline__ int vrow(int d) { return d * 264 + 8 * (d >> 3); }

__launch_bounds__(512)
__global__ void attn(const us* __restrict__ Qb, const us* __restrict__ Kb,
                     const us* __restrict__ Vb, us* __restrict__ PO,
                     float* __restrict__ PL)
{
    const int h = blockIdx.x;
    const int z = blockIdx.y;
    const int s = blockIdx.z;
    const int e = z >> 4, b = z & 15;
    const int tid  = threadIdx.x;
    const int w    = tid >> 6;
    const int lane = tid & 63;
    const int l15  = lane & 15, quad = lane >> 4;
    __shared__ us Ks[256 * 32];
    __shared__ us Vs[8464];
    __shared__ us Ps[7][16 * 40];

    const int key0 = s * 256;
    {
        const int kl  = lane >> 2;
        const int seg = lane & 3;
        const us* kg = Kb + ((size_t)((e * 1024 + key0 + w * 16 + kl) * 16 + b)) * 256
                          + h * 32 + seg * 8;
        gld_lds16(kg, &Ks[w * 512]);
        gld_lds16(kg + (size_t)128 * 16 * 256, &Ks[4096 + w * 512]);

        const int kv = tid >> 2;
        const int sg = tid & 3;
        const us* vg = Vb + ((size_t)((e * 1024 + key0 + kv) * 16 + b)) * 256
                          + h * 32 + sg * 8;
        u32x4 v0 = *reinterpret_cast<const u32x4*>(vg);
        u32x4 v1 = *reinterpret_cast<const u32x4*>(vg + (size_t)128 * 16 * 256);
#pragma unroll
        for (int j = 0; j < 4; ++j) {
            const int d0 = sg * 8 + 2 * j;
            const int e0 = vrow(d0);
            const int e1 = e0 + 264;
            Vs[e0 + kv]       = (us)(v0[j] & 0xffff);
            Vs[e1 + kv]       = (us)(v0[j] >> 16);
            Vs[e0 + 128 + kv] = (us)(v1[j] & 0xffff);
            Vs[e1 + 128 + kv] = (us)(v1[j] >> 16);
        }
    }
    u32x4 qraw = {0u, 0u, 0u, 0u};
    if (w < 7) {
        const int l = w * 16 + l15;
        if (l < 100)
            qraw = *reinterpret_cast<const u32x4*>(
                Qb + ((size_t)((e * 100 + l) * 16 + b)) * 256 + h * 32 + quad * 8);
    }
    const bf16x8 qf = __builtin_bit_cast(bf16x8, qraw);

    __syncthreads();

    if (w >= 7) return;

    const f32x4 zacc = {};
    f32x4 o0 = {}, o1 = {};
    float lsum = 0.0f;

    for (int c = 0; c < 8; ++c) {
        bf16x8 kf0 = ld_bf8(&Ks[(c * 32 + l15) * 32 + quad * 8]);
        bf16x8 kf1 = ld_bf8(&Ks[(c * 32 + 16 + l15) * 32 + quad * 8]);
        f32x4 s0 = __builtin_amdgcn_mfma_f32_16x16x32_bf16(kf0, qf, zacc, 0, 0, 0);
        f32x4 s1 = __builtin_amdgcn_mfma_f32_16x16x32_bf16(kf1, qf, zacc, 0, 0, 0);
        float p0[4], p1[4];
#pragma unroll
        for (int r = 0; r < 4; ++r) {
            p0[r] = __expf(s0[r]);
            p1[r] = __expf(s1[r]);
            lsum += p0[r] + p1[r];
        }
        u32x2 w0, w1;
        w0[0] = pack2(p0[0], p0[1]);
        w0[1] = pack2(p0[2], p0[3]);
        w1[0] = pack2(p1[0], p1[1]);
        w1[1] = pack2(p1[2], p1[3]);
        *reinterpret_cast<u32x2*>(&Ps[w][l15 * 40 + quad * 4])      = w0;
        *reinterpret_cast<u32x2*>(&Ps[w][l15 * 40 + 16 + quad * 4]) = w1;
        bf16x8 pf  = ld_bf8(&Ps[w][l15 * 40 + quad * 8]);
        bf16x8 vf0 = ld_bf8(&Vs[vrow(l15) + c * 32 + quad * 8]);
        bf16x8 vf1 = ld_bf8(&Vs[vrow(16 + l15) + c * 32 + quad * 8]);
        o0 = __builtin_amdgcn_mfma_f32_16x16x32_bf16(pf, vf0, o0, 0, 0, 0);
        o1 = __builtin_amdgcn_mfma_f32_16x16x32_bf16(pf, vf1, o1, 0, 0, 0);
    }

    lsum += __shfl_xor(lsum, 16, 64);
    lsum += __shfl_xor(lsum, 32, 64);

#pragma unroll
    for (int r = 0; r < 4; ++r) {
        const int row = w * 16 + quad * 4 + r;
        if (row < 100) {
            const size_t o = (((size_t)((s * 5 + e) * 100 + row)) * 16 + b) * 256 + h * 32;
            PO[o + l15]      = f2bf(o0[r]);
            PO[o + 16 + l15] = f2bf(o1[r]);
        }
    }
    const int q = w * 16 + l15;
    if (quad == 0 && q < 100)
        PL[((((size_t)s * 5 + e) * 16 + b) * 8 + h) * 128 + q] = lsum;
}

// ---------------- gate-weighted mix + residual + LayerNorm -----------------
__launch_bounds__(256)
__global__ void finalize(const float* __restrict__ tgt, const float* __restrict__ Gate,
                         const float* __restrict__ OUTf,
                         const float* __restrict__ gamma, const float* __restrict__ beta,
                         float* __restrict__ out)
{
    const int row = blockIdx.x;
    const int d = threadIdx.x;
    __shared__ float red[8];
    const float t = tgt[(size_t)row * 256 + d];

    float mo = 0.0f;
#pragma unroll
    for (int e = 0; e < 5; ++e)
        mo += Gate[row * 5 + e] * OUTf[((size_t)e * 1600 + row) * 256 + d];
    const float x = t + mo;

    float p1 = x, p2 = x * x;
#pragma unroll
    for (int off = 32; off >= 1; off >>= 1) {
        p1 += __shfl_xor(p1, off, 64);
        p2 += __shfl_xor(p2, off, 64);
    }
    if ((d & 63) == 0) { red[d >> 6] = p1; red[4 + (d >> 6)] = p2; }
    __syncthreads();
    const float mean = (red[0] + red[1] + red[2] + red[3]) * (1.0f / 256.0f);
    const float msq  = (red[4] + red[5] + red[6] + red[7]) * (1.0f / 256.0f);
    const float var  = msq - mean * mean;

    out[(size_t)row * 256 + d] = (x - mean) * rsqrtf(var + 1e-5f) * gamma[d] + beta[d];
}

// ---------------------------------------------------------------------------
extern "C" void kernel_launch(void* const* d_in, const int* in_sizes, int n_in,
                              void* d_out, int out_size, void* d_ws, size_t ws_size,
                              hipStream_t stream)
{
    const float* tgt    = (const float*)d_in[0];
    const float* mem    = (const float*)d_in[1];
    const float* qpos   = (const float*)d_in[2];
    const float* pos    = (const float*)d_in[3];
    const float* w_in   = (const float*)d_in[4];
    const float* b_in   = (const float*)d_in[5];
    const float* w_out  = (const float*)d_in[6];
    const float* b_out  = (const float*)d_in[7];
    const float* w_gate = (const float*)d_in[8];
    const float* b_gate = (const float*)d_in[9];
    const float* ln_g   = (const float*)d_in[10];
    const float* ln_b   = (const float*)d_in[11];
    float* out = (float*)d_out;

    char* p = (char*)d_ws;
    auto alloc = [&](size_t n) { char* r = p; p += (n + 255) & ~(size_t)255; return r; };

    us* Aq   = (us*)alloc(409600ull * 2);       // dead after gemm_qkv
    us* Ak   = (us*)alloc(4194304ull * 2);      // dead after gemm_qkv
    us* Av   = (us*)alloc(4194304ull * 2);      // dead after gemm_qkv
    us* Wb   = (us*)alloc(983040ull * 2);
    us* WOb  = (us*)alloc(327680ull * 2);
    us* Qb   = (us*)alloc(5ull * 409600 * 2);
    us* Kb   = (us*)alloc(5ull * 4194304 * 2);
    us* Vb   = (us*)alloc(5ull * 4194304 * 2);
    float* OUTf  = (float*)alloc(5ull * 409600 * 4);
    float* Gate  = (float*)alloc(1600ull * 5 * 4);
    // Attention partials alias the dead cvt region (Aq..Av): 16.4+0.33 < 17.7 MB
    us*    PO = (us*)d_ws;                          // [4][5][100][16][256] bf16
    float* PL = (float*)((char*)d_ws + 16384000);   // [4*5*16*8][128] f32

    cvt_all<<<5776, 256, 0, stream>>>(tgt, qpos, mem, pos, w_in, w_out,
                                      w_gate, b_gate, Aq, Ak, Av, Wb, WOb, Gate);

    gemm_qkv<<<dim3(128, 2, 15), 256, 0, stream>>>(Aq, Ak, Av, Wb, b_in, Qb, Kb, Vb);

    attn<<<dim3(8, 80, 4), 512, 0, stream>>>(Qb, Kb, Vb, PO, PL);

    gemm_og<<<dim3(13, 2, 5), 256, 0, stream>>>(PO, PL, WOb, b_out, OUTf);

    finalize<<<1600, 256, 0, stream>>>(tgt, Gate, OUTf, ln_g, ln_b, out);
}

// Round 6
// 200.643 us; speedup vs baseline: 1.1251x; 1.0228x over previous
//
#include <hip/hip_runtime.h>

// ---------------------------------------------------------------------------
// MoE cross-attention decoder layer on MI355X (gfx950), bf16 MFMA pipeline.
// R15: attn split-K reduced 4 -> 2 (each block loops 2 x 256-key chunks,
// accumulating o/lsum in registers): PO write 16.4->8.2 MB, gemm_og PO read
// 33->16.4 MB, Q re-reads halved, blocks 2560->1280 (=5/CU, better balance).
// gemm_og reads/sums 2 splits (POr[4][2], -32 VGPR). gemm_qkv kept at R14
// (55.5 us = concurrency floor for this structure; FETCH 20 MB XCD-aligned
// verified). cvt_all / finalize unchanged.
// ---------------------------------------------------------------------------

typedef __bf16 bf16x8 __attribute__((ext_vector_type(8)));
typedef float f32x4 __attribute__((ext_vector_type(4)));
typedef unsigned int u32x4 __attribute__((ext_vector_type(4)));
typedef unsigned int u32x2 __attribute__((ext_vector_type(2)));
typedef unsigned short u16x4 __attribute__((ext_vector_type(4)));
typedef unsigned short us;

__device__ __forceinline__ us f2bf(float f) {
    unsigned u = __builtin_bit_cast(unsigned, f);
    u += 0x7FFFu + ((u >> 16) & 1u);
    return (us)(u >> 16);
}

__device__ __forceinline__ unsigned pack2(float lo, float hi) {
    return (unsigned)f2bf(lo) | ((unsigned)f2bf(hi) << 16);
}

__device__ __forceinline__ float bf2f(us v) {
    unsigned u = ((unsigned)v) << 16;
    return __builtin_bit_cast(float, u);
}

__device__ __forceinline__ bf16x8 ld_bf8(const us* p) {
    return __builtin_bit_cast(bf16x8, *reinterpret_cast<const u32x4*>(p));
}

__device__ __forceinline__ void gld_lds16(const us* g, us* l) {
    __builtin_amdgcn_global_load_lds(
        (const __attribute__((address_space(1))) unsigned int*)g,
        (__attribute__((address_space(3))) unsigned int*)l, 16, 0, 0);
}

// ---------------- fused converts + gate softmax ----------------------------
// Wb is written FRAGMENT-MAJOR: per (e,role) 65536-elem block laid out as
// [g 0..31][col 0..255][8], g = k/8.
__launch_bounds__(256)
__global__ void cvt_all(const float* __restrict__ tgt, const float* __restrict__ qpos,
                        const float* __restrict__ mem, const float* __restrict__ pos,
                        const float* __restrict__ w_in, const float* __restrict__ w_out,
                        const float* __restrict__ w_gate, const float* __restrict__ b_gate,
                        us* __restrict__ Aq, us* __restrict__ Ak, us* __restrict__ Av,
                        us* __restrict__ Wb, us* __restrict__ WOb,
                        float* __restrict__ Gate)
{
    const int bid = blockIdx.x;
    const int tid = threadIdx.x;
    if (bid < 400) {
        const int i = bid * 256 + tid;
        const int lane = tid & 63;
        const int row = i >> 6;                 // = 4*bid + wave
        f32x4 a = reinterpret_cast<const f32x4*>(tgt)[i];
        f32x4 b = reinterpret_cast<const f32x4*>(qpos)[i];
        u16x4 r;
#pragma unroll
        for (int j = 0; j < 4; ++j) r[j] = f2bf(a[j] + b[j]);
        reinterpret_cast<u16x4*>(Aq)[i] = r;
        float g[5];
#pragma unroll
        for (int e = 0; e < 5; ++e) {
            f32x4 wg = *reinterpret_cast<const f32x4*>(w_gate + e * 256 + 4 * lane);
            float p = a[0] * wg[0] + a[1] * wg[1] + a[2] * wg[2] + a[3] * wg[3];
#pragma unroll
            for (int off = 32; off >= 1; off >>= 1) p += __shfl_xor(p, off, 64);
            g[e] = p + b_gate[e];
        }
        float mx = g[0];
#pragma unroll
        for (int e = 1; e < 5; ++e) mx = fmaxf(mx, g[e]);
        float sm = 0.0f;
#pragma unroll
        for (int e = 0; e < 5; ++e) { g[e] = __expf(g[e] - mx); sm += g[e]; }
        const float invs = 1.0f / sm;
        if (lane == 0) {
#pragma unroll
            for (int e = 0; e < 5; ++e) Gate[row * 5 + e] = g[e] * invs;
        }
    } else if (bid < 4496) {
        int i = (bid - 400) * 256 + tid;
        f32x4 m = reinterpret_cast<const f32x4*>(mem)[i];
        f32x4 p = reinterpret_cast<const f32x4*>(pos)[i];
        u16x4 rk, rv;
#pragma unroll
        for (int j = 0; j < 4; ++j) { rk[j] = f2bf(m[j] + p[j]); rv[j] = f2bf(m[j]); }
        reinterpret_cast<u16x4*>(Ak)[i] = rk;
        reinterpret_cast<u16x4*>(Av)[i] = rv;
    } else if (bid < 5456) {
        int i = (bid - 4496) * 256 + tid;       // f32x4 index into w_in
        f32x4 a = reinterpret_cast<const f32x4*>(w_in)[i];
        u16x4 r;
#pragma unroll
        for (int j = 0; j < 4; ++j) r[j] = f2bf(a[j]);
        const int e    = i / 49152;             // 768*64
        const int rem  = i % 49152;
        const int row  = rem >> 6;              // 0..767
        const int kq4  = rem & 63;
        const int role = row >> 8;              // 0=q 1=k 2=v
        const int col  = row & 255;
        const int g    = kq4 >> 1;              // k granule (8 elems)
        const int sub  = kq4 & 1;
        const size_t dst = (size_t)(e * 3 + role) * 65536
                         + ((size_t)(g * 256 + col)) * 8 + sub * 4;
        *reinterpret_cast<u16x4*>(Wb + dst) = r;
    } else {
        int i = (bid - 5456) * 256 + tid;
        f32x4 a = reinterpret_cast<const f32x4*>(w_out)[i];
        u16x4 r;
#pragma unroll
        for (int j = 0; j < 4; ++j) r[j] = f2bf(a[j]);
        reinterpret_cast<u16x4*>(WOb)[i] = r;
    }
}

// ---------------- QKV projection (R14, unchanged) --------------------------
__launch_bounds__(256, 4)
__global__ void gemm_qkv(const us* __restrict__ Aq, const us* __restrict__ Ak,
                         const us* __restrict__ Av, const us* __restrict__ Wb,
                         const float* __restrict__ b_in,
                         us* __restrict__ Qb, us* __restrict__ Kb, us* __restrict__ Vb)
{
    const int rb   = blockIdx.x;       // row block
    const int col0 = blockIdx.y * 128;
    const int zr   = blockIdx.z;       // role-expert
    const us* A; const us* W; const float* bias; us* C;
    float scale; int M;
    if (zr < 5) {
        if (rb >= 13) return;
        A = Aq; W = Wb + (size_t)zr * 196608; bias = b_in + (size_t)zr * 768;
        C = Qb + (size_t)zr * 409600; scale = 0.17677669529663687f; M = 1600;
    } else if (zr < 10) {
        const int e = zr - 5;
        A = Ak; W = Wb + 65536 + (size_t)e * 196608; bias = b_in + (size_t)e * 768 + 256;
        C = Kb + (size_t)e * 4194304; scale = 1.0f; M = 16384;
    } else {
        const int e = zr - 10;
        A = Av; W = Wb + 131072 + (size_t)e * 196608; bias = b_in + (size_t)e * 768 + 512;
        C = Vb + (size_t)e * 4194304; scale = 1.0f; M = 16384;
    }
    const int row0 = rb * 128;

    __shared__ us As[2 * 8192];
    const int tid  = threadIdx.x;
    const int lane = tid & 63;
    const int w    = tid >> 6;
    const int l15  = lane & 15;
    const int quad = lane >> 4;
    const int wm   = (w >> 1) * 64;
    const int wn   = (w & 1) * 64;
    const int srow = lane >> 3;
    const int gofs = ((lane & 7) ^ srow) * 8;

    auto stageA = [&](int buf, int kt) {
#pragma unroll
        for (int cc = 0; cc < 4; ++cc) {
            const int c = w * 4 + cc;
            gld_lds16(A + (size_t)(row0 + c * 8 + srow) * 256 + kt * 64 + gofs,
                      &As[buf * 8192 + c * 512]);
        }
    };

    f32x4 acc[4][4] = {};

    stageA(0, 0);
    __builtin_amdgcn_sched_barrier(0);

#pragma unroll
    for (int kt = 0; kt < 4; ++kt) {
        const int cur = kt & 1;
        u32x4 bf[2][4];
#pragma unroll
        for (int kh = 0; kh < 2; ++kh)
#pragma unroll
            for (int ni = 0; ni < 4; ++ni)
                bf[kh][ni] = *reinterpret_cast<const u32x4*>(
                    W + (((size_t)(kt * 8 + kh * 4 + quad) * 256
                          + (col0 + wn + ni * 16 + l15)) * 8));
        __builtin_amdgcn_sched_barrier(0);
        if (kt < 3) stageA(cur ^ 1, kt + 1);
        __builtin_amdgcn_sched_barrier(0);
        if (kt < 3) asm volatile("s_waitcnt vmcnt(4)" ::: "memory");
        else        asm volatile("s_waitcnt vmcnt(0)" ::: "memory");
        __builtin_amdgcn_s_barrier();
        __builtin_amdgcn_sched_barrier(0);
#pragma unroll
        for (int kh = 0; kh < 2; ++kh) {
            bf16x8 af[4];
#pragma unroll
            for (int mi = 0; mi < 4; ++mi) {
                const int row = wm + mi * 16 + l15;
                const int seg = (kh * 4 + quad) ^ (row & 7);
                af[mi] = ld_bf8(&As[cur * 8192 + row * 64 + seg * 8]);
            }
#pragma unroll
            for (int mi = 0; mi < 4; ++mi)
#pragma unroll
                for (int ni = 0; ni < 4; ++ni)
                    acc[mi][ni] = __builtin_amdgcn_mfma_f32_16x16x32_bf16(
                        __builtin_bit_cast(bf16x8, bf[kh][ni]), af[mi], acc[mi][ni], 0, 0, 0);
        }
        if (kt < 3) {
            asm volatile("s_waitcnt lgkmcnt(0)" ::: "memory");
            __builtin_amdgcn_sched_barrier(0);
            __builtin_amdgcn_s_barrier();
            __builtin_amdgcn_sched_barrier(0);
        }
    }

#pragma unroll
    for (int mi = 0; mi < 4; ++mi) {
        const int row = row0 + wm + mi * 16 + l15;
        if (row < M) {
#pragma unroll
            for (int ni = 0; ni < 4; ++ni) {
                const int colb = col0 + wn + ni * 16 + quad * 4;
                const f32x4 b4 = *reinterpret_cast<const f32x4*>(bias + colb);
                u32x2 pk;
                pk[0] = pack2((acc[mi][ni][0] + b4[0]) * scale,
                              (acc[mi][ni][1] + b4[1]) * scale);
                pk[1] = pack2((acc[mi][ni][2] + b4[2]) * scale,
                              (acc[mi][ni][3] + b4[3]) * scale);
                *reinterpret_cast<u32x2*>(C + (size_t)row * 256 + colb) = pk;
            }
        }
    }
}

// ---------------- out-proj GEMM with fused split-combine (2 splits) --------
__launch_bounds__(256)
__global__ void gemm_og(const us* __restrict__ PO, const float* __restrict__ PL,
                        const us* __restrict__ WOb, const float* __restrict__ b_out,
                        float* __restrict__ OUTf)
{
    const int e = blockIdx.z;
    const us* W = WOb + (size_t)e * 65536;
    const float* bias = b_out + (size_t)e * 256;
    float* Cout = OUTf + (size_t)e * 409600;

    const int row0 = blockIdx.x * 128;
    const int col0 = blockIdx.y * 128;
    __shared__ us As[2 * 8192];
    __shared__ us Bs[2 * 8192];
    const int tid  = threadIdx.x;
    const int lane = tid & 63;
    const int w    = tid >> 6;
    const int l15  = lane & 15;
    const int quad = lane >> 4;
    const int wm   = (w >> 1) * 64;
    const int wn   = (w & 1) * 64;
    const int srow = lane >> 3;
    const int gofs = ((lane & 7) ^ srow) * 8;

    u32x4 POr[4][2];   // [chunk][split]
    float Lr[4];

    auto loadA = [&](int kt) {
#pragma unroll
        for (int cc = 0; cc < 4; ++cc) {
            const int c = w * 4 + cc;
            int grow = row0 + c * 8 + srow;
            if (grow > 1599) grow = 1599;
            const int d0 = kt * 64 + gofs;
            const size_t base = (size_t)e * 409600 + (size_t)grow * 256 + d0;
#pragma unroll
            for (int s = 0; s < 2; ++s)
                POr[cc][s] = *reinterpret_cast<const u32x4*>(PO + base + (size_t)s * 2048000);
            const int l = grow >> 4, bb = grow & 15, hh = d0 >> 5;
            float L = 0.0f;
#pragma unroll
            for (int s = 0; s < 2; ++s)
                L += PL[((((size_t)s * 5 + e) * 16 + bb) * 8 + hh) * 128 + l];
            Lr[cc] = L;
        }
    };
    auto writeA = [&](int buf) {
#pragma unroll
        for (int cc = 0; cc < 4; ++cc) {
            const float inv = 1.0f / Lr[cc];
            u32x4 pk;
#pragma unroll
            for (int j = 0; j < 4; ++j) {
                float v0 = 0.0f, v1 = 0.0f;
#pragma unroll
                for (int s = 0; s < 2; ++s) {
                    const unsigned u = POr[cc][s][j];
                    v0 += __builtin_bit_cast(float, u << 16);
                    v1 += __builtin_bit_cast(float, u & 0xffff0000u);
                }
                pk[j] = pack2(v0 * inv, v1 * inv);
            }
            *reinterpret_cast<u32x4*>(&As[buf * 8192 + (w * 4 + cc) * 512 + lane * 8]) = pk;
        }
    };
    auto loadW = [&](int buf, int kt) {
#pragma unroll
        for (int cc = 0; cc < 4; ++cc) {
            const int c = w * 4 + cc;
            const int row = c * 8 + srow;
            gld_lds16(W + (size_t)(col0 + row) * 256 + kt * 64 + gofs,
                      &Bs[buf * 8192 + c * 512]);
        }
    };

    loadA(0);
    loadW(0, 0);
    writeA(0);
    __syncthreads();

    f32x4 acc[4][4] = {};

#pragma unroll
    for (int kt = 0; kt < 4; ++kt) {
        const int cur = kt & 1;
        if (kt < 3) {
            loadA(kt + 1);
            loadW(cur ^ 1, kt + 1);
        }
#pragma unroll
        for (int kh = 0; kh < 2; ++kh) {
            bf16x8 af[4], bf[4];
#pragma unroll
            for (int mi = 0; mi < 4; ++mi) {
                const int row = wm + mi * 16 + l15;
                const int seg = (kh * 4 + quad) ^ (row & 7);
                af[mi] = ld_bf8(&As[cur * 8192 + row * 64 + seg * 8]);
            }
#pragma unroll
            for (int ni = 0; ni < 4; ++ni) {
                const int col = wn + ni * 16 + l15;
                const int seg = (kh * 4 + quad) ^ (col & 7);
                bf[ni] = ld_bf8(&Bs[cur * 8192 + col * 64 + seg * 8]);
            }
#pragma unroll
            for (int mi = 0; mi < 4; ++mi)
#pragma unroll
                for (int ni = 0; ni < 4; ++ni)
                    acc[mi][ni] = __builtin_amdgcn_mfma_f32_16x16x32_bf16(bf[ni], af[mi], acc[mi][ni], 0, 0, 0);
        }
        if (kt < 3) {
            writeA(cur ^ 1);
            __syncthreads();
        }
    }

#pragma unroll
    for (int mi = 0; mi < 4; ++mi) {
        const int row = row0 + wm + mi * 16 + l15;
        if (row < 1600) {
#pragma unroll
            for (int ni = 0; ni < 4; ++ni) {
                const int colb = col0 + wn + ni * 16 + quad * 4;
                const f32x4 b4 = *reinterpret_cast<const f32x4*>(bias + colb);
                f32x4 v;
#pragma unroll
                for (int r = 0; r < 4; ++r) v[r] = acc[mi][ni][r] + b4[r];
                *reinterpret_cast<f32x4*>(Cout + (size_t)row * 256 + colb) = v;
            }
        }
    }
}

// ---------------- split-K attention (R15: 2 chunks of 256 keys per block) --
__device__ __forceinline__ int vrow(int d) { return d * 264 + 8 * (d >> 3); }

__launch_bounds__(512)
__global__ void attn(const us* __restrict__ Qb, const us* __restrict__ Kb,
                     const us* __restrict__ Vb, us* __restrict__ PO,
                     float* __restrict__ PL)
{
    const int h = blockIdx.x;
    const int z = blockIdx.y;
    const int sp = blockIdx.z;      // split 0/1, each covers 512 keys
    const int e = z >> 4, b = z & 15;
    const int tid  = threadIdx.x;
    const int w    = tid >> 6;
    const int lane = tid & 63;
    const int l15  = lane & 15, quad = lane >> 4;
    __shared__ us Ks[256 * 32];
    __shared__ us Vs[8464];
    __shared__ us Ps[7][16 * 40];

    // Q fragment loaded once
    u32x4 qraw = {0u, 0u, 0u, 0u};
    if (w < 7) {
        const int l = w * 16 + l15;
        if (l < 100)
            qraw = *reinterpret_cast<const u32x4*>(
                Qb + ((size_t)((e * 100 + l) * 16 + b)) * 256 + h * 32 + quad * 8);
    }
    const bf16x8 qf = __builtin_bit_cast(bf16x8, qraw);

    const f32x4 zacc = {};
    f32x4 o0 = {}, o1 = {};
    float lsum = 0.0f;

    for (int sc = 0; sc < 2; ++sc) {
        const int key0 = (sp * 2 + sc) * 256;
        if (sc) __syncthreads();    // prior chunk's LDS reads complete
        {
            const int kl  = lane >> 2;
            const int seg = lane & 3;
            const us* kg = Kb + ((size_t)((e * 1024 + key0 + w * 16 + kl) * 16 + b)) * 256
                              + h * 32 + seg * 8;
            gld_lds16(kg, &Ks[w * 512]);
            gld_lds16(kg + (size_t)128 * 16 * 256, &Ks[4096 + w * 512]);

            const int kv = tid >> 2;
            const int sg = tid & 3;
            const us* vg = Vb + ((size_t)((e * 1024 + key0 + kv) * 16 + b)) * 256
                              + h * 32 + sg * 8;
            u32x4 v0 = *reinterpret_cast<const u32x4*>(vg);
            u32x4 v1 = *reinterpret_cast<const u32x4*>(vg + (size_t)128 * 16 * 256);
#pragma unroll
            for (int j = 0; j < 4; ++j) {
                const int d0 = sg * 8 + 2 * j;
                const int e0 = vrow(d0);
                const int e1 = e0 + 264;
                Vs[e0 + kv]       = (us)(v0[j] & 0xffff);
                Vs[e1 + kv]       = (us)(v0[j] >> 16);
                Vs[e0 + 128 + kv] = (us)(v1[j] & 0xffff);
                Vs[e1 + 128 + kv] = (us)(v1[j] >> 16);
            }
        }
        __syncthreads();

        if (w < 7) {
            for (int c = 0; c < 8; ++c) {
                bf16x8 kf0 = ld_bf8(&Ks[(c * 32 + l15) * 32 + quad * 8]);
                bf16x8 kf1 = ld_bf8(&Ks[(c * 32 + 16 + l15) * 32 + quad * 8]);
                f32x4 s0 = __builtin_amdgcn_mfma_f32_16x16x32_bf16(kf0, qf, zacc, 0, 0, 0);
                f32x4 s1 = __builtin_amdgcn_mfma_f32_16x16x32_bf16(kf1, qf, zacc, 0, 0, 0);
                float p0[4], p1[4];
#pragma unroll
                for (int r = 0; r < 4; ++r) {
                    p0[r] = __expf(s0[r]);
                    p1[r] = __expf(s1[r]);
                    lsum += p0[r] + p1[r];
                }
                u32x2 w0, w1;
                w0[0] = pack2(p0[0], p0[1]);
                w0[1] = pack2(p0[2], p0[3]);
                w1[0] = pack2(p1[0], p1[1]);
                w1[1] = pack2(p1[2], p1[3]);
                *reinterpret_cast<u32x2*>(&Ps[w][l15 * 40 + quad * 4])      = w0;
                *reinterpret_cast<u32x2*>(&Ps[w][l15 * 40 + 16 + quad * 4]) = w1;
                bf16x8 pf  = ld_bf8(&Ps[w][l15 * 40 + quad * 8]);
                bf16x8 vf0 = ld_bf8(&Vs[vrow(l15) + c * 32 + quad * 8]);
                bf16x8 vf1 = ld_bf8(&Vs[vrow(16 + l15) + c * 32 + quad * 8]);
                o0 = __builtin_amdgcn_mfma_f32_16x16x32_bf16(pf, vf0, o0, 0, 0, 0);
                o1 = __builtin_amdgcn_mfma_f32_16x16x32_bf16(pf, vf1, o1, 0, 0, 0);
            }
        }
    }

    if (w >= 7) return;

    lsum += __shfl_xor(lsum, 16, 64);
    lsum += __shfl_xor(lsum, 32, 64);

#pragma unroll
    for (int r = 0; r < 4; ++r) {
        const int row = w * 16 + quad * 4 + r;
        if (row < 100) {
            const size_t o = (((size_t)((sp * 5 + e) * 100 + row)) * 16 + b) * 256 + h * 32;
            PO[o + l15]      = f2bf(o0[r]);
            PO[o + 16 + l15] = f2bf(o1[r]);
        }
    }
    const int q = w * 16 + l15;
    if (quad == 0 && q < 100)
        PL[((((size_t)sp * 5 + e) * 16 + b) * 8 + h) * 128 + q] = lsum;
}

// ---------------- gate-weighted mix + residual + LayerNorm -----------------
__launch_bounds__(256)
__global__ void finalize(const float* __restrict__ tgt, const float* __restrict__ Gate,
                         const float* __restrict__ OUTf,
                         const float* __restrict__ gamma, const float* __restrict__ beta,
                         float* __restrict__ out)
{
    const int row = blockIdx.x;
    const int d = threadIdx.x;
    __shared__ float red[8];
    const float t = tgt[(size_t)row * 256 + d];

    float mo = 0.0f;
#pragma unroll
    for (int e = 0; e < 5; ++e)
        mo += Gate[row * 5 + e] * OUTf[((size_t)e * 1600 + row) * 256 + d];
    const float x = t + mo;

    float p1 = x, p2 = x * x;
#pragma unroll
    for (int off = 32; off >= 1; off >>= 1) {
        p1 += __shfl_xor(p1, off, 64);
        p2 += __shfl_xor(p2, off, 64);
    }
    if ((d & 63) == 0) { red[d >> 6] = p1; red[4 + (d >> 6)] = p2; }
    __syncthreads();
    const float mean = (red[0] + red[1] + red[2] + red[3]) * (1.0f / 256.0f);
    const float msq  = (red[4] + red[5] + red[6] + red[7]) * (1.0f / 256.0f);
    const float var  = msq - mean * mean;

    out[(size_t)row * 256 + d] = (x - mean) * rsqrtf(var + 1e-5f) * gamma[d] + beta[d];
}

// ---------------------------------------------------------------------------
extern "C" void kernel_launch(void* const* d_in, const int* in_sizes, int n_in,
                              void* d_out, int out_size, void* d_ws, size_t ws_size,
                              hipStream_t stream)
{
    const float* tgt    = (const float*)d_in[0];
    const float* mem    = (const float*)d_in[1];
    const float* qpos   = (const float*)d_in[2];
    const float* pos    = (const float*)d_in[3];
    const float* w_in   = (const float*)d_in[4];
    const float* b_in   = (const float*)d_in[5];
    const float* w_out  = (const float*)d_in[6];
    const float* b_out  = (const float*)d_in[7];
    const float* w_gate = (const float*)d_in[8];
    const float* b_gate = (const float*)d_in[9];
    const float* ln_g   = (const float*)d_in[10];
    const float* ln_b   = (const float*)d_in[11];
    float* out = (float*)d_out;

    char* p = (char*)d_ws;
    auto alloc = [&](size_t n) { char* r = p; p += (n + 255) & ~(size_t)255; return r; };

    us* Aq   = (us*)alloc(409600ull * 2);       // dead after gemm_qkv
    us* Ak   = (us*)alloc(4194304ull * 2);      // dead after gemm_qkv
    us* Av   = (us*)alloc(4194304ull * 2);      // dead after gemm_qkv
    us* Wb   = (us*)alloc(983040ull * 2);
    us* WOb  = (us*)alloc(327680ull * 2);
    us* Qb   = (us*)alloc(5ull * 409600 * 2);
    us* Kb   = (us*)alloc(5ull * 4194304 * 2);
    us* Vb   = (us*)alloc(5ull * 4194304 * 2);
    float* OUTf  = (float*)alloc(5ull * 409600 * 4);
    float* Gate  = (float*)alloc(1600ull * 5 * 4);
    // Attention partials alias the dead cvt region (Aq..Av): 8.2+0.66 < 17.7 MB
    us*    PO = (us*)d_ws;                          // [2][5][100][16][256] bf16
    float* PL = (float*)((char*)d_ws + 8192000);    // [2*5*16*8][128] f32

    cvt_all<<<5776, 256, 0, stream>>>(tgt, qpos, mem, pos, w_in, w_out,
                                      w_gate, b_gate, Aq, Ak, Av, Wb, WOb, Gate);

    gemm_qkv<<<dim3(128, 2, 15), 256, 0, stream>>>(Aq, Ak, Av, Wb, b_in, Qb, Kb, Vb);

    attn<<<dim3(8, 80, 2), 512, 0, stream>>>(Qb, Kb, Vb, PO, PL);

    gemm_og<<<dim3(13, 2, 5), 256, 0, stream>>>(PO, PL, WOb, b_out, OUTf);

    finalize<<<1600, 256, 0, stream>>>(tgt, Gate, OUTf, ln_g, ln_b, out);
}

// Round 7
// 195.001 us; speedup vs baseline: 1.1577x; 1.0289x over previous
//
#include <hip/hip_runtime.h>

// ---------------------------------------------------------------------------
// MoE cross-attention decoder layer on MI355X (gfx950), bf16 MFMA pipeline.
// R16: XCD-alignment of cache-line sharers (zero-math change, block-id
// remapping only):
//  - attn grid (8,80,2)->(80,8,2): head-siblings (which split 128B K/V/Q
//    lines) now differ by 80 = 0 mod 8 -> same XCD L2 -> K/V fetched once
//    (was 2x: h,h+1 on different XCDs). Expected -~80 MB HBM.
//  - gemm_og grid (13,2,5)->(16,2,5)+guard: col-block pairs (both read the
//    SAME full PO rows) now differ by 16 = 0 mod 8 -> PO fetched once.
// Everything else identical to R15 (qkv @ R14 floor, split-2 attn).
// ---------------------------------------------------------------------------

typedef __bf16 bf16x8 __attribute__((ext_vector_type(8)));
typedef float f32x4 __attribute__((ext_vector_type(4)));
typedef unsigned int u32x4 __attribute__((ext_vector_type(4)));
typedef unsigned int u32x2 __attribute__((ext_vector_type(2)));
typedef unsigned short u16x4 __attribute__((ext_vector_type(4)));
typedef unsigned short us;

__device__ __forceinline__ us f2bf(float f) {
    unsigned u = __builtin_bit_cast(unsigned, f);
    u += 0x7FFFu + ((u >> 16) & 1u);
    return (us)(u >> 16);
}

__device__ __forceinline__ unsigned pack2(float lo, float hi) {
    return (unsigned)f2bf(lo) | ((unsigned)f2bf(hi) << 16);
}

__device__ __forceinline__ float bf2f(us v) {
    unsigned u = ((unsigned)v) << 16;
    return __builtin_bit_cast(float, u);
}

__device__ __forceinline__ bf16x8 ld_bf8(const us* p) {
    return __builtin_bit_cast(bf16x8, *reinterpret_cast<const u32x4*>(p));
}

__device__ __forceinline__ void gld_lds16(const us* g, us* l) {
    __builtin_amdgcn_global_load_lds(
        (const __attribute__((address_space(1))) unsigned int*)g,
        (__attribute__((address_space(3))) unsigned int*)l, 16, 0, 0);
}

// ---------------- fused converts + gate softmax ----------------------------
// Wb is written FRAGMENT-MAJOR: per (e,role) 65536-elem block laid out as
// [g 0..31][col 0..255][8], g = k/8.
__launch_bounds__(256)
__global__ void cvt_all(const float* __restrict__ tgt, const float* __restrict__ qpos,
                        const float* __restrict__ mem, const float* __restrict__ pos,
                        const float* __restrict__ w_in, const float* __restrict__ w_out,
                        const float* __restrict__ w_gate, const float* __restrict__ b_gate,
                        us* __restrict__ Aq, us* __restrict__ Ak, us* __restrict__ Av,
                        us* __restrict__ Wb, us* __restrict__ WOb,
                        float* __restrict__ Gate)
{
    const int bid = blockIdx.x;
    const int tid = threadIdx.x;
    if (bid < 400) {
        const int i = bid * 256 + tid;
        const int lane = tid & 63;
        const int row = i >> 6;                 // = 4*bid + wave
        f32x4 a = reinterpret_cast<const f32x4*>(tgt)[i];
        f32x4 b = reinterpret_cast<const f32x4*>(qpos)[i];
        u16x4 r;
#pragma unroll
        for (int j = 0; j < 4; ++j) r[j] = f2bf(a[j] + b[j]);
        reinterpret_cast<u16x4*>(Aq)[i] = r;
        float g[5];
#pragma unroll
        for (int e = 0; e < 5; ++e) {
            f32x4 wg = *reinterpret_cast<const f32x4*>(w_gate + e * 256 + 4 * lane);
            float p = a[0] * wg[0] + a[1] * wg[1] + a[2] * wg[2] + a[3] * wg[3];
#pragma unroll
            for (int off = 32; off >= 1; off >>= 1) p += __shfl_xor(p, off, 64);
            g[e] = p + b_gate[e];
        }
        float mx = g[0];
#pragma unroll
        for (int e = 1; e < 5; ++e) mx = fmaxf(mx, g[e]);
        float sm = 0.0f;
#pragma unroll
        for (int e = 0; e < 5; ++e) { g[e] = __expf(g[e] - mx); sm += g[e]; }
        const float invs = 1.0f / sm;
        if (lane == 0) {
#pragma unroll
            for (int e = 0; e < 5; ++e) Gate[row * 5 + e] = g[e] * invs;
        }
    } else if (bid < 4496) {
        int i = (bid - 400) * 256 + tid;
        f32x4 m = reinterpret_cast<const f32x4*>(mem)[i];
        f32x4 p = reinterpret_cast<const f32x4*>(pos)[i];
        u16x4 rk, rv;
#pragma unroll
        for (int j = 0; j < 4; ++j) { rk[j] = f2bf(m[j] + p[j]); rv[j] = f2bf(m[j]); }
        reinterpret_cast<u16x4*>(Ak)[i] = rk;
        reinterpret_cast<u16x4*>(Av)[i] = rv;
    } else if (bid < 5456) {
        int i = (bid - 4496) * 256 + tid;       // f32x4 index into w_in
        f32x4 a = reinterpret_cast<const f32x4*>(w_in)[i];
        u16x4 r;
#pragma unroll
        for (int j = 0; j < 4; ++j) r[j] = f2bf(a[j]);
        const int e    = i / 49152;             // 768*64
        const int rem  = i % 49152;
        const int row  = rem >> 6;              // 0..767
        const int kq4  = rem & 63;
        const int role = row >> 8;              // 0=q 1=k 2=v
        const int col  = row & 255;
        const int g    = kq4 >> 1;              // k granule (8 elems)
        const int sub  = kq4 & 1;
        const size_t dst = (size_t)(e * 3 + role) * 65536
                         + ((size_t)(g * 256 + col)) * 8 + sub * 4;
        *reinterpret_cast<u16x4*>(Wb + dst) = r;
    } else {
        int i = (bid - 5456) * 256 + tid;
        f32x4 a = reinterpret_cast<const f32x4*>(w_out)[i];
        u16x4 r;
#pragma unroll
        for (int j = 0; j < 4; ++j) r[j] = f2bf(a[j]);
        reinterpret_cast<u16x4*>(WOb)[i] = r;
    }
}

// ---------------- QKV projection (R14, unchanged) --------------------------
__launch_bounds__(256, 4)
__global__ void gemm_qkv(const us* __restrict__ Aq, const us* __restrict__ Ak,
                         const us* __restrict__ Av, const us* __restrict__ Wb,
                         const float* __restrict__ b_in,
                         us* __restrict__ Qb, us* __restrict__ Kb, us* __restrict__ Vb)
{
    const int rb   = blockIdx.x;       // row block
    const int col0 = blockIdx.y * 128;
    const int zr   = blockIdx.z;       // role-expert
    const us* A; const us* W; const float* bias; us* C;
    float scale; int M;
    if (zr < 5) {
        if (rb >= 13) return;
        A = Aq; W = Wb + (size_t)zr * 196608; bias = b_in + (size_t)zr * 768;
        C = Qb + (size_t)zr * 409600; scale = 0.17677669529663687f; M = 1600;
    } else if (zr < 10) {
        const int e = zr - 5;
        A = Ak; W = Wb + 65536 + (size_t)e * 196608; bias = b_in + (size_t)e * 768 + 256;
        C = Kb + (size_t)e * 4194304; scale = 1.0f; M = 16384;
    } else {
        const int e = zr - 10;
        A = Av; W = Wb + 131072 + (size_t)e * 196608; bias = b_in + (size_t)e * 768 + 512;
        C = Vb + (size_t)e * 4194304; scale = 1.0f; M = 16384;
    }
    const int row0 = rb * 128;

    __shared__ us As[2 * 8192];
    const int tid  = threadIdx.x;
    const int lane = tid & 63;
    const int w    = tid >> 6;
    const int l15  = lane & 15;
    const int quad = lane >> 4;
    const int wm   = (w >> 1) * 64;
    const int wn   = (w & 1) * 64;
    const int srow = lane >> 3;
    const int gofs = ((lane & 7) ^ srow) * 8;

    auto stageA = [&](int buf, int kt) {
#pragma unroll
        for (int cc = 0; cc < 4; ++cc) {
            const int c = w * 4 + cc;
            gld_lds16(A + (size_t)(row0 + c * 8 + srow) * 256 + kt * 64 + gofs,
                      &As[buf * 8192 + c * 512]);
        }
    };

    f32x4 acc[4][4] = {};

    stageA(0, 0);
    __builtin_amdgcn_sched_barrier(0);

#pragma unroll
    for (int kt = 0; kt < 4; ++kt) {
        const int cur = kt & 1;
        u32x4 bf[2][4];
#pragma unroll
        for (int kh = 0; kh < 2; ++kh)
#pragma unroll
            for (int ni = 0; ni < 4; ++ni)
                bf[kh][ni] = *reinterpret_cast<const u32x4*>(
                    W + (((size_t)(kt * 8 + kh * 4 + quad) * 256
                          + (col0 + wn + ni * 16 + l15)) * 8));
        __builtin_amdgcn_sched_barrier(0);
        if (kt < 3) stageA(cur ^ 1, kt + 1);
        __builtin_amdgcn_sched_barrier(0);
        if (kt < 3) asm volatile("s_waitcnt vmcnt(4)" ::: "memory");
        else        asm volatile("s_waitcnt vmcnt(0)" ::: "memory");
        __builtin_amdgcn_s_barrier();
        __builtin_amdgcn_sched_barrier(0);
#pragma unroll
        for (int kh = 0; kh < 2; ++kh) {
            bf16x8 af[4];
#pragma unroll
            for (int mi = 0; mi < 4; ++mi) {
                const int row = wm + mi * 16 + l15;
                const int seg = (kh * 4 + quad) ^ (row & 7);
                af[mi] = ld_bf8(&As[cur * 8192 + row * 64 + seg * 8]);
            }
#pragma unroll
            for (int mi = 0; mi < 4; ++mi)
#pragma unroll
                for (int ni = 0; ni < 4; ++ni)
                    acc[mi][ni] = __builtin_amdgcn_mfma_f32_16x16x32_bf16(
                        __builtin_bit_cast(bf16x8, bf[kh][ni]), af[mi], acc[mi][ni], 0, 0, 0);
        }
        if (kt < 3) {
            asm volatile("s_waitcnt lgkmcnt(0)" ::: "memory");
            __builtin_amdgcn_sched_barrier(0);
            __builtin_amdgcn_s_barrier();
            __builtin_amdgcn_sched_barrier(0);
        }
    }

#pragma unroll
    for (int mi = 0; mi < 4; ++mi) {
        const int row = row0 + wm + mi * 16 + l15;
        if (row < M) {
#pragma unroll
            for (int ni = 0; ni < 4; ++ni) {
                const int colb = col0 + wn + ni * 16 + quad * 4;
                const f32x4 b4 = *reinterpret_cast<const f32x4*>(bias + colb);
                u32x2 pk;
                pk[0] = pack2((acc[mi][ni][0] + b4[0]) * scale,
                              (acc[mi][ni][1] + b4[1]) * scale);
                pk[1] = pack2((acc[mi][ni][2] + b4[2]) * scale,
                              (acc[mi][ni][3] + b4[3]) * scale);
                *reinterpret_cast<u32x2*>(C + (size_t)row * 256 + colb) = pk;
            }
        }
    }
}

// ---------------- out-proj GEMM with fused split-combine (2 splits) --------
// grid (16, 2, 5): x = row block (>=13 idle; pads y-sibling stride to 16 = 0
// mod 8 so both col-blocks' identical PO-row reads hit the same XCD L2).
__launch_bounds__(256)
__global__ void gemm_og(const us* __restrict__ PO, const float* __restrict__ PL,
                        const us* __restrict__ WOb, const float* __restrict__ b_out,
                        float* __restrict__ OUTf)
{
    if (blockIdx.x >= 13) return;
    const int e = blockIdx.z;
    const us* W = WOb + (size_t)e * 65536;
    const float* bias = b_out + (size_t)e * 256;
    float* Cout = OUTf + (size_t)e * 409600;

    const int row0 = blockIdx.x * 128;
    const int col0 = blockIdx.y * 128;
    __shared__ us As[2 * 8192];
    __shared__ us Bs[2 * 8192];
    const int tid  = threadIdx.x;
    const int lane = tid & 63;
    const int w    = tid >> 6;
    const int l15  = lane & 15;
    const int quad = lane >> 4;
    const int wm   = (w >> 1) * 64;
    const int wn   = (w & 1) * 64;
    const int srow = lane >> 3;
    const int gofs = ((lane & 7) ^ srow) * 8;

    u32x4 POr[4][2];   // [chunk][split]
    float Lr[4];

    auto loadA = [&](int kt) {
#pragma unroll
        for (int cc = 0; cc < 4; ++cc) {
            const int c = w * 4 + cc;
            int grow = row0 + c * 8 + srow;
            if (grow > 1599) grow = 1599;
            const int d0 = kt * 64 + gofs;
            const size_t base = (size_t)e * 409600 + (size_t)grow * 256 + d0;
#pragma unroll
            for (int s = 0; s < 2; ++s)
                POr[cc][s] = *reinterpret_cast<const u32x4*>(PO + base + (size_t)s * 2048000);
            const int l = grow >> 4, bb = grow & 15, hh = d0 >> 5;
            float L = 0.0f;
#pragma unroll
            for (int s = 0; s < 2; ++s)
                L += PL[((((size_t)s * 5 + e) * 16 + bb) * 8 + hh) * 128 + l];
            Lr[cc] = L;
        }
    };
    auto writeA = [&](int buf) {
#pragma unroll
        for (int cc = 0; cc < 4; ++cc) {
            const float inv = 1.0f / Lr[cc];
            u32x4 pk;
#pragma unroll
            for (int j = 0; j < 4; ++j) {
                float v0 = 0.0f, v1 = 0.0f;
#pragma unroll
                for (int s = 0; s < 2; ++s) {
                    const unsigned u = POr[cc][s][j];
                    v0 += __builtin_bit_cast(float, u << 16);
                    v1 += __builtin_bit_cast(float, u & 0xffff0000u);
                }
                pk[j] = pack2(v0 * inv, v1 * inv);
            }
            *reinterpret_cast<u32x4*>(&As[buf * 8192 + (w * 4 + cc) * 512 + lane * 8]) = pk;
        }
    };
    auto loadW = [&](int buf, int kt) {
#pragma unroll
        for (int cc = 0; cc < 4; ++cc) {
            const int c = w * 4 + cc;
            const int row = c * 8 + srow;
            gld_lds16(W + (size_t)(col0 + row) * 256 + kt * 64 + gofs,
                      &Bs[buf * 8192 + c * 512]);
        }
    };

    loadA(0);
    loadW(0, 0);
    writeA(0);
    __syncthreads();

    f32x4 acc[4][4] = {};

#pragma unroll
    for (int kt = 0; kt < 4; ++kt) {
        const int cur = kt & 1;
        if (kt < 3) {
            loadA(kt + 1);
            loadW(cur ^ 1, kt + 1);
        }
#pragma unroll
        for (int kh = 0; kh < 2; ++kh) {
            bf16x8 af[4], bf[4];
#pragma unroll
            for (int mi = 0; mi < 4; ++mi) {
                const int row = wm + mi * 16 + l15;
                const int seg = (kh * 4 + quad) ^ (row & 7);
                af[mi] = ld_bf8(&As[cur * 8192 + row * 64 + seg * 8]);
            }
#pragma unroll
            for (int ni = 0; ni < 4; ++ni) {
                const int col = wn + ni * 16 + l15;
                const int seg = (kh * 4 + quad) ^ (col & 7);
                bf[ni] = ld_bf8(&Bs[cur * 8192 + col * 64 + seg * 8]);
            }
#pragma unroll
            for (int mi = 0; mi < 4; ++mi)
#pragma unroll
                for (int ni = 0; ni < 4; ++ni)
                    acc[mi][ni] = __builtin_amdgcn_mfma_f32_16x16x32_bf16(bf[ni], af[mi], acc[mi][ni], 0, 0, 0);
        }
        if (kt < 3) {
            writeA(cur ^ 1);
            __syncthreads();
        }
    }

#pragma unroll
    for (int mi = 0; mi < 4; ++mi) {
        const int row = row0 + wm + mi * 16 + l15;
        if (row < 1600) {
#pragma unroll
            for (int ni = 0; ni < 4; ++ni) {
                const int colb = col0 + wn + ni * 16 + quad * 4;
                const f32x4 b4 = *reinterpret_cast<const f32x4*>(bias + colb);
                f32x4 v;
#pragma unroll
                for (int r = 0; r < 4; ++r) v[r] = acc[mi][ni][r] + b4[r];
                *reinterpret_cast<f32x4*>(Cout + (size_t)row * 256 + colb) = v;
            }
        }
    }
}

// ---------------- split-K attention (R16: XCD-aligned grid) ----------------
// grid (80, 8, 2): x = e*16+b, y = head, z = split. Head-siblings (sharing
// 128B K/V/Q cache lines) differ by 80 in flat id = 0 mod 8 -> same XCD.
__device__ __forceinline__ int vrow(int d) { return d * 264 + 8 * (d >> 3); }

__launch_bounds__(512)
__global__ void attn(const us* __restrict__ Qb, const us* __restrict__ Kb,
                     const us* __restrict__ Vb, us* __restrict__ PO,
                     float* __restrict__ PL)
{
    const int z = blockIdx.x;
    const int h = blockIdx.y;
    const int sp = blockIdx.z;      // split 0/1, each covers 512 keys
    const int e = z >> 4, b = z & 15;
    const int tid  = threadIdx.x;
    const int w    = tid >> 6;
    const int lane = tid & 63;
    const int l15  = lane & 15, quad = lane >> 4;
    __shared__ us Ks[256 * 32];
    __shared__ us Vs[8464];
    __shared__ us Ps[7][16 * 40];

    // Q fragment loaded once
    u32x4 qraw = {0u, 0u, 0u, 0u};
    if (w < 7) {
        const int l = w * 16 + l15;
        if (l < 100)
            qraw = *reinterpret_cast<const u32x4*>(
                Qb + ((size_t)((e * 100 + l) * 16 + b)) * 256 + h * 32 + quad * 8);
    }
    const bf16x8 qf = __builtin_bit_cast(bf16x8, qraw);

    const f32x4 zacc = {};
    f32x4 o0 = {}, o1 = {};
    float lsum = 0.0f;

    for (int sc = 0; sc < 2; ++sc) {
        const int key0 = (sp * 2 + sc) * 256;
        if (sc) __syncthreads();    // prior chunk's LDS reads complete
        {
            const int kl  = lane >> 2;
            const int seg = lane & 3;
            const us* kg = Kb + ((size_t)((e * 1024 + key0 + w * 16 + kl) * 16 + b)) * 256
                              + h * 32 + seg * 8;
            gld_lds16(kg, &Ks[w * 512]);
            gld_lds16(kg + (size_t)128 * 16 * 256, &Ks[4096 + w * 512]);

            const int kv = tid >> 2;
            const int sg = tid & 3;
            const us* vg = Vb + ((size_t)((e * 1024 + key0 + kv) * 16 + b)) * 256
                              + h * 32 + sg * 8;
            u32x4 v0 = *reinterpret_cast<const u32x4*>(vg);
            u32x4 v1 = *reinterpret_cast<const u32x4*>(vg + (size_t)128 * 16 * 256);
#pragma unroll
            for (int j = 0; j < 4; ++j) {
                const int d0 = sg * 8 + 2 * j;
                const int e0 = vrow(d0);
                const int e1 = e0 + 264;
                Vs[e0 + kv]       = (us)(v0[j] & 0xffff);
                Vs[e1 + kv]       = (us)(v0[j] >> 16);
                Vs[e0 + 128 + kv] = (us)(v1[j] & 0xffff);
                Vs[e1 + 128 + kv] = (us)(v1[j] >> 16);
            }
        }
        __syncthreads();

        if (w < 7) {
            for (int c = 0; c < 8; ++c) {
                bf16x8 kf0 = ld_bf8(&Ks[(c * 32 + l15) * 32 + quad * 8]);
                bf16x8 kf1 = ld_bf8(&Ks[(c * 32 + 16 + l15) * 32 + quad * 8]);
                f32x4 s0 = __builtin_amdgcn_mfma_f32_16x16x32_bf16(kf0, qf, zacc, 0, 0, 0);
                f32x4 s1 = __builtin_amdgcn_mfma_f32_16x16x32_bf16(kf1, qf, zacc, 0, 0, 0);
                float p0[4], p1[4];
#pragma unroll
                for (int r = 0; r < 4; ++r) {
                    p0[r] = __expf(s0[r]);
                    p1[r] = __expf(s1[r]);
                    lsum += p0[r] + p1[r];
                }
                u32x2 w0, w1;
                w0[0] = pack2(p0[0], p0[1]);
                w0[1] = pack2(p0[2], p0[3]);
                w1[0] = pack2(p1[0], p1[1]);
                w1[1] = pack2(p1[2], p1[3]);
                *reinterpret_cast<u32x2*>(&Ps[w][l15 * 40 + quad * 4])      = w0;
                *reinterpret_cast<u32x2*>(&Ps[w][l15 * 40 + 16 + quad * 4]) = w1;
                bf16x8 pf  = ld_bf8(&Ps[w][l15 * 40 + quad * 8]);
                bf16x8 vf0 = ld_bf8(&Vs[vrow(l15) + c * 32 + quad * 8]);
                bf16x8 vf1 = ld_bf8(&Vs[vrow(16 + l15) + c * 32 + quad * 8]);
                o0 = __builtin_amdgcn_mfma_f32_16x16x32_bf16(pf, vf0, o0, 0, 0, 0);
                o1 = __builtin_amdgcn_mfma_f32_16x16x32_bf16(pf, vf1, o1, 0, 0, 0);
            }
        }
    }

    if (w >= 7) return;

    lsum += __shfl_xor(lsum, 16, 64);
    lsum += __shfl_xor(lsum, 32, 64);

#pragma unroll
    for (int r = 0; r < 4; ++r) {
        const int row = w * 16 + quad * 4 + r;
        if (row < 100) {
            const size_t o = (((size_t)((sp * 5 + e) * 100 + row)) * 16 + b) * 256 + h * 32;
            PO[o + l15]      = f2bf(o0[r]);
            PO[o + 16 + l15] = f2bf(o1[r]);
        }
    }
    const int q = w * 16 + l15;
    if (quad == 0 && q < 100)
        PL[((((size_t)sp * 5 + e) * 16 + b) * 8 + h) * 128 + q] = lsum;
}

// ---------------- gate-weighted mix + residual + LayerNorm -----------------
__launch_bounds__(256)
__global__ void finalize(const float* __restrict__ tgt, const float* __restrict__ Gate,
                         const float* __restrict__ OUTf,
                         const float* __restrict__ gamma, const float* __restrict__ beta,
                         float* __restrict__ out)
{
    const int row = blockIdx.x;
    const int d = threadIdx.x;
    __shared__ float red[8];
    const float t = tgt[(size_t)row * 256 + d];

    float mo = 0.0f;
#pragma unroll
    for (int e = 0; e < 5; ++e)
        mo += Gate[row * 5 + e] * OUTf[((size_t)e * 1600 + row) * 256 + d];
    const float x = t + mo;

    float p1 = x, p2 = x * x;
#pragma unroll
    for (int off = 32; off >= 1; off >>= 1) {
        p1 += __shfl_xor(p1, off, 64);
        p2 += __shfl_xor(p2, off, 64);
    }
    if ((d & 63) == 0) { red[d >> 6] = p1; red[4 + (d >> 6)] = p2; }
    __syncthreads();
    const float mean = (red[0] + red[1] + red[2] + red[3]) * (1.0f / 256.0f);
    const float msq  = (red[4] + red[5] + red[6] + red[7]) * (1.0f / 256.0f);
    const float var  = msq - mean * mean;

    out[(size_t)row * 256 + d] = (x - mean) * rsqrtf(var + 1e-5f) * gamma[d] + beta[d];
}

// ---------------------------------------------------------------------------
extern "C" void kernel_launch(void* const* d_in, const int* in_sizes, int n_in,
                              void* d_out, int out_size, void* d_ws, size_t ws_size,
                              hipStream_t stream)
{
    const float* tgt    = (const float*)d_in[0];
    const float* mem    = (const float*)d_in[1];
    const float* qpos   = (const float*)d_in[2];
    const float* pos    = (const float*)d_in[3];
    const float* w_in   = (const float*)d_in[4];
    const float* b_in   = (const float*)d_in[5];
    const float* w_out  = (const float*)d_in[6];
    const float* b_out  = (const float*)d_in[7];
    const float* w_gate = (const float*)d_in[8];
    const float* b_gate = (const float*)d_in[9];
    const float* ln_g   = (const float*)d_in[10];
    const float* ln_b   = (const float*)d_in[11];
    float* out = (float*)d_out;

    char* p = (char*)d_ws;
    auto alloc = [&](size_t n) { char* r = p; p += (n + 255) & ~(size_t)255; return r; };

    us* Aq   = (us*)alloc(409600ull * 2);       // dead after gemm_qkv
    us* Ak   = (us*)alloc(4194304ull * 2);      // dead after gemm_qkv
    us* Av   = (us*)alloc(4194304ull * 2);      // dead after gemm_qkv
    us* Wb   = (us*)alloc(983040ull * 2);
    us* WOb  = (us*)alloc(327680ull * 2);
    us* Qb   = (us*)alloc(5ull * 409600 * 2);
    us* Kb   = (us*)alloc(5ull * 4194304 * 2);
    us* Vb   = (us*)alloc(5ull * 4194304 * 2);
    float* OUTf  = (float*)alloc(5ull * 409600 * 4);
    float* Gate  = (float*)alloc(1600ull * 5 * 4);
    // Attention partials alias the dead cvt region (Aq..Av): 8.2+0.66 < 17.7 MB
    us*    PO = (us*)d_ws;                          // [2][5][100][16][256] bf16
    float* PL = (float*)((char*)d_ws + 8192000);    // [2*5*16*8][128] f32

    cvt_all<<<5776, 256, 0, stream>>>(tgt, qpos, mem, pos, w_in, w_out,
                                      w_gate, b_gate, Aq, Ak, Av, Wb, WOb, Gate);

    gemm_qkv<<<dim3(128, 2, 15), 256, 0, stream>>>(Aq, Ak, Av, Wb, b_in, Qb, Kb, Vb);

    attn<<<dim3(80, 8, 2), 512, 0, stream>>>(Qb, Kb, Vb, PO, PL);

    gemm_og<<<dim3(16, 2, 5), 256, 0, stream>>>(PO, PL, WOb, b_out, OUTf);

    finalize<<<1600, 256, 0, stream>>>(tgt, Gate, OUTf, ln_g, ln_b, out);
}

// Round 8
// 192.437 us; speedup vs baseline: 1.1731x; 1.0133x over previous
//
#include <hip/hip_runtime.h>

// ---------------------------------------------------------------------------
// MoE cross-attention decoder layer on MI355X (gfx950), bf16 MFMA pipeline.
// R17: attn inner loop software-pipelined. The per-chunk chain
// QK-MFMA -> exp(VALU) -> pack -> ds_write -> ds_read -> PV-MFMA was fully
// serial x16 chunks. Now Ps is double-buffered per wave and the loop runs
// qk(c) ; pv(c-1), so PV's ds_read/V-loads/MFMAs (independent of qk(c))
// overlap the exp VALU work on the other pipe. Bit-identical math.
// Everything else frozen at R16 (qkv @ R14 floor; XCD-aligned grids:
// attn (80,8,2), gemm_og (16,2,5)+guard — model verified 3x).
// ---------------------------------------------------------------------------

typedef __bf16 bf16x8 __attribute__((ext_vector_type(8)));
typedef float f32x4 __attribute__((ext_vector_type(4)));
typedef unsigned int u32x4 __attribute__((ext_vector_type(4)));
typedef unsigned int u32x2 __attribute__((ext_vector_type(2)));
typedef unsigned short u16x4 __attribute__((ext_vector_type(4)));
typedef unsigned short us;

__device__ __forceinline__ us f2bf(float f) {
    unsigned u = __builtin_bit_cast(unsigned, f);
    u += 0x7FFFu + ((u >> 16) & 1u);
    return (us)(u >> 16);
}

__device__ __forceinline__ unsigned pack2(float lo, float hi) {
    return (unsigned)f2bf(lo) | ((unsigned)f2bf(hi) << 16);
}

__device__ __forceinline__ float bf2f(us v) {
    unsigned u = ((unsigned)v) << 16;
    return __builtin_bit_cast(float, u);
}

__device__ __forceinline__ bf16x8 ld_bf8(const us* p) {
    return __builtin_bit_cast(bf16x8, *reinterpret_cast<const u32x4*>(p));
}

__device__ __forceinline__ void gld_lds16(const us* g, us* l) {
    __builtin_amdgcn_global_load_lds(
        (const __attribute__((address_space(1))) unsigned int*)g,
        (__attribute__((address_space(3))) unsigned int*)l, 16, 0, 0);
}

// ---------------- fused converts + gate softmax ----------------------------
// Wb is written FRAGMENT-MAJOR: per (e,role) 65536-elem block laid out as
// [g 0..31][col 0..255][8], g = k/8.
__launch_bounds__(256)
__global__ void cvt_all(const float* __restrict__ tgt, const float* __restrict__ qpos,
                        const float* __restrict__ mem, const float* __restrict__ pos,
                        const float* __restrict__ w_in, const float* __restrict__ w_out,
                        const float* __restrict__ w_gate, const float* __restrict__ b_gate,
                        us* __restrict__ Aq, us* __restrict__ Ak, us* __restrict__ Av,
                        us* __restrict__ Wb, us* __restrict__ WOb,
                        float* __restrict__ Gate)
{
    const int bid = blockIdx.x;
    const int tid = threadIdx.x;
    if (bid < 400) {
        const int i = bid * 256 + tid;
        const int lane = tid & 63;
        const int row = i >> 6;                 // = 4*bid + wave
        f32x4 a = reinterpret_cast<const f32x4*>(tgt)[i];
        f32x4 b = reinterpret_cast<const f32x4*>(qpos)[i];
        u16x4 r;
#pragma unroll
        for (int j = 0; j < 4; ++j) r[j] = f2bf(a[j] + b[j]);
        reinterpret_cast<u16x4*>(Aq)[i] = r;
        float g[5];
#pragma unroll
        for (int e = 0; e < 5; ++e) {
            f32x4 wg = *reinterpret_cast<const f32x4*>(w_gate + e * 256 + 4 * lane);
            float p = a[0] * wg[0] + a[1] * wg[1] + a[2] * wg[2] + a[3] * wg[3];
#pragma unroll
            for (int off = 32; off >= 1; off >>= 1) p += __shfl_xor(p, off, 64);
            g[e] = p + b_gate[e];
        }
        float mx = g[0];
#pragma unroll
        for (int e = 1; e < 5; ++e) mx = fmaxf(mx, g[e]);
        float sm = 0.0f;
#pragma unroll
        for (int e = 0; e < 5; ++e) { g[e] = __expf(g[e] - mx); sm += g[e]; }
        const float invs = 1.0f / sm;
        if (lane == 0) {
#pragma unroll
            for (int e = 0; e < 5; ++e) Gate[row * 5 + e] = g[e] * invs;
        }
    } else if (bid < 4496) {
        int i = (bid - 400) * 256 + tid;
        f32x4 m = reinterpret_cast<const f32x4*>(mem)[i];
        f32x4 p = reinterpret_cast<const f32x4*>(pos)[i];
        u16x4 rk, rv;
#pragma unroll
        for (int j = 0; j < 4; ++j) { rk[j] = f2bf(m[j] + p[j]); rv[j] = f2bf(m[j]); }
        reinterpret_cast<u16x4*>(Ak)[i] = rk;
        reinterpret_cast<u16x4*>(Av)[i] = rv;
    } else if (bid < 5456) {
        int i = (bid - 4496) * 256 + tid;       // f32x4 index into w_in
        f32x4 a = reinterpret_cast<const f32x4*>(w_in)[i];
        u16x4 r;
#pragma unroll
        for (int j = 0; j < 4; ++j) r[j] = f2bf(a[j]);
        const int e    = i / 49152;             // 768*64
        const int rem  = i % 49152;
        const int row  = rem >> 6;              // 0..767
        const int kq4  = rem & 63;
        const int role = row >> 8;              // 0=q 1=k 2=v
        const int col  = row & 255;
        const int g    = kq4 >> 1;              // k granule (8 elems)
        const int sub  = kq4 & 1;
        const size_t dst = (size_t)(e * 3 + role) * 65536
                         + ((size_t)(g * 256 + col)) * 8 + sub * 4;
        *reinterpret_cast<u16x4*>(Wb + dst) = r;
    } else {
        int i = (bid - 5456) * 256 + tid;
        f32x4 a = reinterpret_cast<const f32x4*>(w_out)[i];
        u16x4 r;
#pragma unroll
        for (int j = 0; j < 4; ++j) r[j] = f2bf(a[j]);
        reinterpret_cast<u16x4*>(WOb)[i] = r;
    }
}

// ---------------- QKV projection (R14, unchanged) --------------------------
__launch_bounds__(256, 4)
__global__ void gemm_qkv(const us* __restrict__ Aq, const us* __restrict__ Ak,
                         const us* __restrict__ Av, const us* __restrict__ Wb,
                         const float* __restrict__ b_in,
                         us* __restrict__ Qb, us* __restrict__ Kb, us* __restrict__ Vb)
{
    const int rb   = blockIdx.x;       // row block
    const int col0 = blockIdx.y * 128;
    const int zr   = blockIdx.z;       // role-expert
    const us* A; const us* W; const float* bias; us* C;
    float scale; int M;
    if (zr < 5) {
        if (rb >= 13) return;
        A = Aq; W = Wb + (size_t)zr * 196608; bias = b_in + (size_t)zr * 768;
        C = Qb + (size_t)zr * 409600; scale = 0.17677669529663687f; M = 1600;
    } else if (zr < 10) {
        const int e = zr - 5;
        A = Ak; W = Wb + 65536 + (size_t)e * 196608; bias = b_in + (size_t)e * 768 + 256;
        C = Kb + (size_t)e * 4194304; scale = 1.0f; M = 16384;
    } else {
        const int e = zr - 10;
        A = Av; W = Wb + 131072 + (size_t)e * 196608; bias = b_in + (size_t)e * 768 + 512;
        C = Vb + (size_t)e * 4194304; scale = 1.0f; M = 16384;
    }
    const int row0 = rb * 128;

    __shared__ us As[2 * 8192];
    const int tid  = threadIdx.x;
    const int lane = tid & 63;
    const int w    = tid >> 6;
    const int l15  = lane & 15;
    const int quad = lane >> 4;
    const int wm   = (w >> 1) * 64;
    const int wn   = (w & 1) * 64;
    const int srow = lane >> 3;
    const int gofs = ((lane & 7) ^ srow) * 8;

    auto stageA = [&](int buf, int kt) {
#pragma unroll
        for (int cc = 0; cc < 4; ++cc) {
            const int c = w * 4 + cc;
            gld_lds16(A + (size_t)(row0 + c * 8 + srow) * 256 + kt * 64 + gofs,
                      &As[buf * 8192 + c * 512]);
        }
    };

    f32x4 acc[4][4] = {};

    stageA(0, 0);
    __builtin_amdgcn_sched_barrier(0);

#pragma unroll
    for (int kt = 0; kt < 4; ++kt) {
        const int cur = kt & 1;
        u32x4 bf[2][4];
#pragma unroll
        for (int kh = 0; kh < 2; ++kh)
#pragma unroll
            for (int ni = 0; ni < 4; ++ni)
                bf[kh][ni] = *reinterpret_cast<const u32x4*>(
                    W + (((size_t)(kt * 8 + kh * 4 + quad) * 256
                          + (col0 + wn + ni * 16 + l15)) * 8));
        __builtin_amdgcn_sched_barrier(0);
        if (kt < 3) stageA(cur ^ 1, kt + 1);
        __builtin_amdgcn_sched_barrier(0);
        if (kt < 3) asm volatile("s_waitcnt vmcnt(4)" ::: "memory");
        else        asm volatile("s_waitcnt vmcnt(0)" ::: "memory");
        __builtin_amdgcn_s_barrier();
        __builtin_amdgcn_sched_barrier(0);
#pragma unroll
        for (int kh = 0; kh < 2; ++kh) {
            bf16x8 af[4];
#pragma unroll
            for (int mi = 0; mi < 4; ++mi) {
                const int row = wm + mi * 16 + l15;
                const int seg = (kh * 4 + quad) ^ (row & 7);
                af[mi] = ld_bf8(&As[cur * 8192 + row * 64 + seg * 8]);
            }
#pragma unroll
            for (int mi = 0; mi < 4; ++mi)
#pragma unroll
                for (int ni = 0; ni < 4; ++ni)
                    acc[mi][ni] = __builtin_amdgcn_mfma_f32_16x16x32_bf16(
                        __builtin_bit_cast(bf16x8, bf[kh][ni]), af[mi], acc[mi][ni], 0, 0, 0);
        }
        if (kt < 3) {
            asm volatile("s_waitcnt lgkmcnt(0)" ::: "memory");
            __builtin_amdgcn_sched_barrier(0);
            __builtin_amdgcn_s_barrier();
            __builtin_amdgcn_sched_barrier(0);
        }
    }

#pragma unroll
    for (int mi = 0; mi < 4; ++mi) {
        const int row = row0 + wm + mi * 16 + l15;
        if (row < M) {
#pragma unroll
            for (int ni = 0; ni < 4; ++ni) {
                const int colb = col0 + wn + ni * 16 + quad * 4;
                const f32x4 b4 = *reinterpret_cast<const f32x4*>(bias + colb);
                u32x2 pk;
                pk[0] = pack2((acc[mi][ni][0] + b4[0]) * scale,
                              (acc[mi][ni][1] + b4[1]) * scale);
                pk[1] = pack2((acc[mi][ni][2] + b4[2]) * scale,
                              (acc[mi][ni][3] + b4[3]) * scale);
                *reinterpret_cast<u32x2*>(C + (size_t)row * 256 + colb) = pk;
            }
        }
    }
}

// ---------------- out-proj GEMM with fused split-combine (2 splits) --------
// grid (16, 2, 5): x = row block (>=13 idle; pads y-sibling stride to 16 = 0
// mod 8 so both col-blocks' identical PO-row reads hit the same XCD L2).
__launch_bounds__(256)
__global__ void gemm_og(const us* __restrict__ PO, const float* __restrict__ PL,
                        const us* __restrict__ WOb, const float* __restrict__ b_out,
                        float* __restrict__ OUTf)
{
    if (blockIdx.x >= 13) return;
    const int e = blockIdx.z;
    const us* W = WOb + (size_t)e * 65536;
    const float* bias = b_out + (size_t)e * 256;
    float* Cout = OUTf + (size_t)e * 409600;

    const int row0 = blockIdx.x * 128;
    const int col0 = blockIdx.y * 128;
    __shared__ us As[2 * 8192];
    __shared__ us Bs[2 * 8192];
    const int tid  = threadIdx.x;
    const int lane = tid & 63;
    const int w    = tid >> 6;
    const int l15  = lane & 15;
    const int quad = lane >> 4;
    const int wm   = (w >> 1) * 64;
    const int wn   = (w & 1) * 64;
    const int srow = lane >> 3;
    const int gofs = ((lane & 7) ^ srow) * 8;

    u32x4 POr[4][2];   // [chunk][split]
    float Lr[4];

    auto loadA = [&](int kt) {
#pragma unroll
        for (int cc = 0; cc < 4; ++cc) {
            const int c = w * 4 + cc;
            int grow = row0 + c * 8 + srow;
            if (grow > 1599) grow = 1599;
            const int d0 = kt * 64 + gofs;
            const size_t base = (size_t)e * 409600 + (size_t)grow * 256 + d0;
#pragma unroll
            for (int s = 0; s < 2; ++s)
                POr[cc][s] = *reinterpret_cast<const u32x4*>(PO + base + (size_t)s * 2048000);
            const int l = grow >> 4, bb = grow & 15, hh = d0 >> 5;
            float L = 0.0f;
#pragma unroll
            for (int s = 0; s < 2; ++s)
                L += PL[((((size_t)s * 5 + e) * 16 + bb) * 8 + hh) * 128 + l];
            Lr[cc] = L;
        }
    };
    auto writeA = [&](int buf) {
#pragma unroll
        for (int cc = 0; cc < 4; ++cc) {
            const float inv = 1.0f / Lr[cc];
            u32x4 pk;
#pragma unroll
            for (int j = 0; j < 4; ++j) {
                float v0 = 0.0f, v1 = 0.0f;
#pragma unroll
                for (int s = 0; s < 2; ++s) {
                    const unsigned u = POr[cc][s][j];
                    v0 += __builtin_bit_cast(float, u << 16);
                    v1 += __builtin_bit_cast(float, u & 0xffff0000u);
                }
                pk[j] = pack2(v0 * inv, v1 * inv);
            }
            *reinterpret_cast<u32x4*>(&As[buf * 8192 + (w * 4 + cc) * 512 + lane * 8]) = pk;
        }
    };
    auto loadW = [&](int buf, int kt) {
#pragma unroll
        for (int cc = 0; cc < 4; ++cc) {
            const int c = w * 4 + cc;
            const int row = c * 8 + srow;
            gld_lds16(W + (size_t)(col0 + row) * 256 + kt * 64 + gofs,
                      &Bs[buf * 8192 + c * 512]);
        }
    };

    loadA(0);
    loadW(0, 0);
    writeA(0);
    __syncthreads();

    f32x4 acc[4][4] = {};

#pragma unroll
    for (int kt = 0; kt < 4; ++kt) {
        const int cur = kt & 1;
        if (kt < 3) {
            loadA(kt + 1);
            loadW(cur ^ 1, kt + 1);
        }
#pragma unroll
        for (int kh = 0; kh < 2; ++kh) {
            bf16x8 af[4], bf[4];
#pragma unroll
            for (int mi = 0; mi < 4; ++mi) {
                const int row = wm + mi * 16 + l15;
                const int seg = (kh * 4 + quad) ^ (row & 7);
                af[mi] = ld_bf8(&As[cur * 8192 + row * 64 + seg * 8]);
            }
#pragma unroll
            for (int ni = 0; ni < 4; ++ni) {
                const int col = wn + ni * 16 + l15;
                const int seg = (kh * 4 + quad) ^ (col & 7);
                bf[ni] = ld_bf8(&Bs[cur * 8192 + col * 64 + seg * 8]);
            }
#pragma unroll
            for (int mi = 0; mi < 4; ++mi)
#pragma unroll
                for (int ni = 0; ni < 4; ++ni)
                    acc[mi][ni] = __builtin_amdgcn_mfma_f32_16x16x32_bf16(bf[ni], af[mi], acc[mi][ni], 0, 0, 0);
        }
        if (kt < 3) {
            writeA(cur ^ 1);
            __syncthreads();
        }
    }

#pragma unroll
    for (int mi = 0; mi < 4; ++mi) {
        const int row = row0 + wm + mi * 16 + l15;
        if (row < 1600) {
#pragma unroll
            for (int ni = 0; ni < 4; ++ni) {
                const int colb = col0 + wn + ni * 16 + quad * 4;
                const f32x4 b4 = *reinterpret_cast<const f32x4*>(bias + colb);
                f32x4 v;
#pragma unroll
                for (int r = 0; r < 4; ++r) v[r] = acc[mi][ni][r] + b4[r];
                *reinterpret_cast<f32x4*>(Cout + (size_t)row * 256 + colb) = v;
            }
        }
    }
}

// ---------------- split-K attention (R17: pipelined QK/exp vs PV) ----------
// grid (80, 8, 2): x = e*16+b, y = head, z = split (XCD-aligned, R16).
__device__ __forceinline__ int vrow(int d) { return d * 264 + 8 * (d >> 3); }

__launch_bounds__(512)
__global__ void attn(const us* __restrict__ Qb, const us* __restrict__ Kb,
                     const us* __restrict__ Vb, us* __restrict__ PO,
                     float* __restrict__ PL)
{
    const int z = blockIdx.x;
    const int h = blockIdx.y;
    const int sp = blockIdx.z;      // split 0/1, each covers 512 keys
    const int e = z >> 4, b = z & 15;
    const int tid  = threadIdx.x;
    const int w    = tid >> 6;
    const int lane = tid & 63;
    const int l15  = lane & 15, quad = lane >> 4;
    __shared__ us Ks[256 * 32];
    __shared__ us Vs[8464];
    __shared__ us Ps[7][2][16 * 40];   // double-buffered per wave

    // Q fragment loaded once
    u32x4 qraw = {0u, 0u, 0u, 0u};
    if (w < 7) {
        const int l = w * 16 + l15;
        if (l < 100)
            qraw = *reinterpret_cast<const u32x4*>(
                Qb + ((size_t)((e * 100 + l) * 16 + b)) * 256 + h * 32 + quad * 8);
    }
    const bf16x8 qf = __builtin_bit_cast(bf16x8, qraw);

    const f32x4 zacc = {};
    f32x4 o0 = {}, o1 = {};
    float lsum = 0.0f;

    for (int sc = 0; sc < 2; ++sc) {
        const int key0 = (sp * 2 + sc) * 256;
        if (sc) __syncthreads();    // prior chunk's LDS reads complete
        {
            const int kl  = lane >> 2;
            const int seg = lane & 3;
            const us* kg = Kb + ((size_t)((e * 1024 + key0 + w * 16 + kl) * 16 + b)) * 256
                              + h * 32 + seg * 8;
            gld_lds16(kg, &Ks[w * 512]);
            gld_lds16(kg + (size_t)128 * 16 * 256, &Ks[4096 + w * 512]);

            const int kv = tid >> 2;
            const int sg = tid & 3;
            const us* vg = Vb + ((size_t)((e * 1024 + key0 + kv) * 16 + b)) * 256
                              + h * 32 + sg * 8;
            u32x4 v0 = *reinterpret_cast<const u32x4*>(vg);
            u32x4 v1 = *reinterpret_cast<const u32x4*>(vg + (size_t)128 * 16 * 256);
#pragma unroll
            for (int j = 0; j < 4; ++j) {
                const int d0 = sg * 8 + 2 * j;
                const int e0 = vrow(d0);
                const int e1 = e0 + 264;
                Vs[e0 + kv]       = (us)(v0[j] & 0xffff);
                Vs[e1 + kv]       = (us)(v0[j] >> 16);
                Vs[e0 + 128 + kv] = (us)(v1[j] & 0xffff);
                Vs[e1 + 128 + kv] = (us)(v1[j] >> 16);
            }
        }
        __syncthreads();

        if (w < 7) {
            // qk(c): QK^T MFMA + exp + pack -> Ps[w][c&1]
            auto qk = [&](int c) {
                bf16x8 kf0 = ld_bf8(&Ks[(c * 32 + l15) * 32 + quad * 8]);
                bf16x8 kf1 = ld_bf8(&Ks[(c * 32 + 16 + l15) * 32 + quad * 8]);
                f32x4 s0 = __builtin_amdgcn_mfma_f32_16x16x32_bf16(kf0, qf, zacc, 0, 0, 0);
                f32x4 s1 = __builtin_amdgcn_mfma_f32_16x16x32_bf16(kf1, qf, zacc, 0, 0, 0);
                float p0[4], p1[4];
#pragma unroll
                for (int r = 0; r < 4; ++r) {
                    p0[r] = __expf(s0[r]);
                    p1[r] = __expf(s1[r]);
                    lsum += p0[r] + p1[r];
                }
                u32x2 w0, w1;
                w0[0] = pack2(p0[0], p0[1]);
                w0[1] = pack2(p0[2], p0[3]);
                w1[0] = pack2(p1[0], p1[1]);
                w1[1] = pack2(p1[2], p1[3]);
                us* psb = &Ps[w][c & 1][0];
                *reinterpret_cast<u32x2*>(&psb[l15 * 40 + quad * 4])      = w0;
                *reinterpret_cast<u32x2*>(&psb[l15 * 40 + 16 + quad * 4]) = w1;
            };
            // pv(c): P(c) x V(c) from Ps[w][c&1]
            auto pv = [&](int c) {
                bf16x8 pf  = ld_bf8(&Ps[w][c & 1][l15 * 40 + quad * 8]);
                bf16x8 vf0 = ld_bf8(&Vs[vrow(l15) + c * 32 + quad * 8]);
                bf16x8 vf1 = ld_bf8(&Vs[vrow(16 + l15) + c * 32 + quad * 8]);
                o0 = __builtin_amdgcn_mfma_f32_16x16x32_bf16(pf, vf0, o0, 0, 0, 0);
                o1 = __builtin_amdgcn_mfma_f32_16x16x32_bf16(pf, vf1, o1, 0, 0, 0);
            };
            qk(0);
#pragma unroll
            for (int c = 1; c < 8; ++c) {
                qk(c);      // exp VALU of chunk c ...
                pv(c - 1);  // ... overlaps PV MFMA of chunk c-1
            }
            pv(7);
        }
    }

    if (w >= 7) return;

    lsum += __shfl_xor(lsum, 16, 64);
    lsum += __shfl_xor(lsum, 32, 64);

#pragma unroll
    for (int r = 0; r < 4; ++r) {
        const int row = w * 16 + quad * 4 + r;
        if (row < 100) {
            const size_t o = (((size_t)((sp * 5 + e) * 100 + row)) * 16 + b) * 256 + h * 32;
            PO[o + l15]      = f2bf(o0[r]);
            PO[o + 16 + l15] = f2bf(o1[r]);
        }
    }
    const int q = w * 16 + l15;
    if (quad == 0 && q < 100)
        PL[((((size_t)sp * 5 + e) * 16 + b) * 8 + h) * 128 + q] = lsum;
}

// ---------------- gate-weighted mix + residual + LayerNorm -----------------
__launch_bounds__(256)
__global__ void finalize(const float* __restrict__ tgt, const float* __restrict__ Gate,
                         const float* __restrict__ OUTf,
                         const float* __restrict__ gamma, const float* __restrict__ beta,
                         float* __restrict__ out)
{
    const int row = blockIdx.x;
    const int d = threadIdx.x;
    __shared__ float red[8];
    const float t = tgt[(size_t)row * 256 + d];

    float mo = 0.0f;
#pragma unroll
    for (int e = 0; e < 5; ++e)
        mo += Gate[row * 5 + e] * OUTf[((size_t)e * 1600 + row) * 256 + d];
    const float x = t + mo;

    float p1 = x, p2 = x * x;
#pragma unroll
    for (int off = 32; off >= 1; off >>= 1) {
        p1 += __shfl_xor(p1, off, 64);
        p2 += __shfl_xor(p2, off, 64);
    }
    if ((d & 63) == 0) { red[d >> 6] = p1; red[4 + (d >> 6)] = p2; }
    __syncthreads();
    const float mean = (red[0] + red[1] + red[2] + red[3]) * (1.0f / 256.0f);
    const float msq  = (red[4] + red[5] + red[6] + red[7]) * (1.0f / 256.0f);
    const float var  = msq - mean * mean;

    out[(size_t)row * 256 + d] = (x - mean) * rsqrtf(var + 1e-5f) * gamma[d] + beta[d];
}

// ---------------------------------------------------------------------------
extern "C" void kernel_launch(void* const* d_in, const int* in_sizes, int n_in,
                              void* d_out, int out_size, void* d_ws, size_t ws_size,
                              hipStream_t stream)
{
    const float* tgt    = (const float*)d_in[0];
    const float* mem    = (const float*)d_in[1];
    const float* qpos   = (const float*)d_in[2];
    const float* pos    = (const float*)d_in[3];
    const float* w_in   = (const float*)d_in[4];
    const float* b_in   = (const float*)d_in[5];
    const float* w_out  = (const float*)d_in[6];
    const float* b_out  = (const float*)d_in[7];
    const float* w_gate = (const float*)d_in[8];
    const float* b_gate = (const float*)d_in[9];
    const float* ln_g   = (const float*)d_in[10];
    const float* ln_b   = (const float*)d_in[11];
    float* out = (float*)d_out;

    char* p = (char*)d_ws;
    auto alloc = [&](size_t n) { char* r = p; p += (n + 255) & ~(size_t)255; return r; };

    us* Aq   = (us*)alloc(409600ull * 2);       // dead after gemm_qkv
    us* Ak   = (us*)alloc(4194304ull * 2);      // dead after gemm_qkv
    us* Av   = (us*)alloc(4194304ull * 2);      // dead after gemm_qkv
    us* Wb   = (us*)alloc(983040ull * 2);
    us* WOb  = (us*)alloc(327680ull * 2);
    us* Qb   = (us*)alloc(5ull * 409600 * 2);
    us* Kb   = (us*)alloc(5ull * 4194304 * 2);
    us* Vb   = (us*)alloc(5ull * 4194304 * 2);
    float* OUTf  = (float*)alloc(5ull * 409600 * 4);
    float* Gate  = (float*)alloc(1600ull * 5 * 4);
    // Attention partials alias the dead cvt region (Aq..Av): 8.2+0.66 < 17.7 MB
    us*    PO = (us*)d_ws;                          // [2][5][100][16][256] bf16
    float* PL = (float*)((char*)d_ws + 8192000);    // [2*5*16*8][128] f32

    cvt_all<<<5776, 256, 0, stream>>>(tgt, qpos, mem, pos, w_in, w_out,
                                      w_gate, b_gate, Aq, Ak, Av, Wb, WOb, Gate);

    gemm_qkv<<<dim3(128, 2, 15), 256, 0, stream>>>(Aq, Ak, Av, Wb, b_in, Qb, Kb, Vb);

    attn<<<dim3(80, 8, 2), 512, 0, stream>>>(Qb, Kb, Vb, PO, PL);

    gemm_og<<<dim3(16, 2, 5), 256, 0, stream>>>(PO, PL, WOb, b_out, OUTf);

    finalize<<<1600, 256, 0, stream>>>(tgt, Gate, OUTf, ln_g, ln_b, out);
}